// Round 12
// baseline (223.042 us; speedup 1.0000x reference)
//
#include <hip/hip_runtime.h>

// ---------------------------------------------------------------------------
// DeBERTa-v2 disentangled self-attention, MI355X (gfx950)
// B=2, L=1024, D=1024, H=16, HEAD=64, ATT_SPAN=256 (pos dim 512), scale=sqrt(192)
// ---------------------------------------------------------------------------

typedef short s8v __attribute__((ext_vector_type(8)));
typedef short s4v __attribute__((ext_vector_type(4)));
typedef float f32x4 __attribute__((ext_vector_type(4)));
typedef float f4v __attribute__((ext_vector_type(4)));

#define QK_SCALE 0.26864243f   // 192^(-1/4); folded so all score terms get /sqrt(192)

__device__ __forceinline__ unsigned short f2bf(float f) {
  unsigned u = __builtin_bit_cast(unsigned, f);
  u += 0x7fffu + ((u >> 16) & 1u);          // RNE
  return (unsigned short)(u >> 16);
}
__device__ __forceinline__ float bf2f(unsigned short h) {
  unsigned u = ((unsigned)h) << 16;
  return __builtin_bit_cast(float, u);
}

__device__ __forceinline__ void gload_lds16(const void* g, void* l) {
  __builtin_amdgcn_global_load_lds(
      (const __attribute__((address_space(1))) void*)g,
      (__attribute__((address_space(3))) void*)l, 16, 0, 0);
}

// ---------------------------------------------------------------------------
// prep: f32->bf16 conversions, bucket table, mask bias
// ---------------------------------------------------------------------------
__global__ __launch_bounds__(256) void prep_kernel(
    const float* __restrict__ hidden, const float* __restrict__ rel,
    const float* __restrict__ Wq, const float* __restrict__ Wk,
    const float* __restrict__ Wv, const int* __restrict__ mask,
    short* __restrict__ Abf, short* __restrict__ Wbf,
    float* __restrict__ mbias, short* __restrict__ Tt) {
  int idx = blockIdx.x * 256 + threadIdx.x;
  const int NCONV = 1441792;  // (2560*1024 + 3*1024*1024)/4 float4s
  if (idx < NCONV) {
    const float* src; short* dst; int off;
    if (idx < 524288) { src = hidden; dst = Abf; off = idx; }
    else if (idx < 655360) { src = rel; dst = Abf + 2048 * 1024; off = idx - 524288; }
    else {
      int j = idx - 655360;
      int w = j / 262144; off = j - w * 262144;
      src = (w == 0) ? Wq : (w == 1) ? Wk : Wv;
      dst = Wbf + w * 1048576;
    }
    f4v v = ((const f4v*)src)[off];
    s4v o;
    o[0] = (short)f2bf(v[0]); o[1] = (short)f2bf(v[1]);
    o[2] = (short)f2bf(v[2]); o[3] = (short)f2bf(v[3]);
    ((s4v*)dst)[off] = o;
  } else {
    int j = idx - NCONV;
    if (j < 2047) {
      int r = j - 1023;
      float fr = (float)r;
      float sign = (r > 0) ? 1.f : ((r < 0) ? -1.f : 0.f);
      float abs_pos = (r < 128 && r > -128) ? 127.f : fabsf(fr);
      const float logc = 1.3843393245589053f;  // f32(log(511/128))
      float log_pos = ceilf(logf(abs_pos * (1.f / 128.f)) / logc * 127.f) + 128.f;
      float bucket = (abs_pos <= 128.f) ? fr : log_pos * sign;
      int bi = (int)bucket + 256;
      bi = bi < 0 ? 0 : (bi > 511 ? 511 : bi);
      Tt[j] = (short)bi;
    } else if (j < 4095) {
      int m = j - 2047;
      mbias[m] = (mask[m] > 0) ? 0.f : -1e9f;
    }
  }
}

// ---------------------------------------------------------------------------
// gemm_qkv: C[m,n] = (sum_k A[m,k]*W[n,k] + bias[n]) * scale, bf16 out
//   128x128 tile, XOR-SWIZZLED LDS (R9: conflicts 8.26M -> fixed).
//   z==2 (V): position rows (>=2048) never consumed -> early exit.
// ---------------------------------------------------------------------------
__global__ __launch_bounds__(256) void gemm_qkv(
    const short* __restrict__ Abf, const short* __restrict__ Wbf,
    const float* __restrict__ bq, const float* __restrict__ bk,
    const float* __restrict__ bv,
    short* __restrict__ Qc, short* __restrict__ Kc, short* __restrict__ Vc) {
  __shared__ short As[128 * 64];
  __shared__ short Bs[128 * 64];
  int tid = threadIdx.x;
  int wid = tid >> 6, lane = tid & 63;
  int lr = lane & 15, lg = lane >> 4;
  int wr = wid >> 1, wc = wid & 1;
  int z = blockIdx.z;
  int brow = blockIdx.y * 128;
  if (z == 2 && brow >= 2048) return;   // V pos-rows unused
  const short* W = Wbf + z * 1048576;
  const float* bias = (z == 0) ? bq : (z == 1) ? bk : bv;
  short* C = (z == 0) ? Qc : (z == 1) ? Kc : Vc;
  float scale = (z == 2) ? 1.f : QK_SCALE;
  int bcol = blockIdx.x * 128;

  f32x4 acc[4][4];
  for (int i = 0; i < 4; i++)
    for (int j = 0; j < 4; j++) acc[i][j] = (f32x4){0.f, 0.f, 0.f, 0.f};

  for (int k0 = 0; k0 < 1024; k0 += 64) {
    for (int i = 0; i < 4; i++) {
      int n = i * 256 + wid * 64 + lane;
      int row = n >> 3, cswz = n & 7, cb = cswz ^ (row & 7);
      const short* gA = Abf + (size_t)(brow + row) * 1024 + k0 + cb * 8;
      gload_lds16(gA, &As[(i * 256 + wid * 64) * 8]);
      const short* gB = W + (size_t)(bcol + row) * 1024 + k0 + cb * 8;
      gload_lds16(gB, &Bs[(i * 256 + wid * 64) * 8]);
    }
    __syncthreads();
    for (int ks = 0; ks < 2; ks++) {
      s8v af[4], bfv[4];
      for (int mi = 0; mi < 4; mi++) {
        int row = wr * 64 + mi * 16 + lr, cb = ks * 4 + lg;
        af[mi] = *(const s8v*)&As[row * 64 + (cb ^ (row & 7)) * 8];
      }
      for (int ni = 0; ni < 4; ni++) {
        int row = wc * 64 + ni * 16 + lr, cb = ks * 4 + lg;
        bfv[ni] = *(const s8v*)&Bs[row * 64 + (cb ^ (row & 7)) * 8];
      }
      for (int mi = 0; mi < 4; mi++)
        for (int ni = 0; ni < 4; ni++)
          acc[mi][ni] = __builtin_amdgcn_mfma_f32_16x16x32_bf16(
              af[mi], bfv[ni], acc[mi][ni], 0, 0, 0);
    }
    __syncthreads();
  }
  for (int mi = 0; mi < 4; mi++)
    for (int ni = 0; ni < 4; ni++) {
      int col = bcol + wc * 64 + ni * 16 + lr;
      float bb = bias[col];
      for (int r = 0; r < 4; r++) {
        int row = brow + wr * 64 + mi * 16 + lg * 4 + r;
        float v = (acc[mi][ni][r] + bb) * scale;
        C[(size_t)row * 1024 + col] = (short)f2bf(v);
      }
    }
}

// ---------------------------------------------------------------------------
// pos_trans: MERGED pos_gemm (z<64) + transpose_v (z>=64).
//   pos part now XOR-SWIZZLED (same fix as gemm_qkv R9: linear [row][64]
//   LDS fragment reads are a 16-way ds_read_b128 bank conflict).
//   pos part:  which=0: c2p[bh][q][p] = Q[q].posK[p]
//              which=1: p2c[bh][k][p] = K[k].posQ[p] + mbias[b,k]
//   trans part: Vt[b,h,d,l] = Vc[b*1024+l, h*64+d]
// ---------------------------------------------------------------------------
__global__ __launch_bounds__(256) void pos_trans(
    const short* __restrict__ Qc, const short* __restrict__ Kc,
    const short* __restrict__ Vc, const float* __restrict__ mbias,
    short* __restrict__ c2p, short* __restrict__ p2c,
    short* __restrict__ Vt) {
  __shared__ short sh[2 * 128 * 64];
  int tid = threadIdx.x;
  if (blockIdx.z < 64) {
    short* As = sh;
    short* Bs = sh + 128 * 64;
    int wid = tid >> 6, lane = tid & 63;
    int lr = lane & 15, lg = lane >> 4;
    int wr = wid >> 1, wc = wid & 1;
    int zz = blockIdx.z;       // 0..63
    int which = zz >> 5;
    int bh = zz & 31;
    int b = bh >> 4, h = bh & 15;
    const short* Arows = (which == 0) ? Qc : Kc;   // content source
    const short* Brows = (which == 0) ? Kc : Qc;   // pos-projection source
    short* Out = (which == 0) ? c2p : p2c;
    int mrow = blockIdx.y * 128;   // content base (1024/128 = 8)
    int ncol = blockIdx.x * 128;   // bucket base  (512/128 = 4)

    for (int i = 0; i < 4; i++) {
      int n = i * 256 + wid * 64 + lane;
      int row = n >> 3, cswz = n & 7, cb = cswz ^ (row & 7);
      const short* gA = Arows + (size_t)(b * 1024 + mrow + row) * 1024 + h * 64 + cb * 8;
      gload_lds16(gA, &As[(i * 256 + wid * 64) * 8]);
      const short* gB = Brows + (size_t)(2048 + ncol + row) * 1024 + h * 64 + cb * 8;
      gload_lds16(gB, &Bs[(i * 256 + wid * 64) * 8]);
    }
    __syncthreads();

    f32x4 acc[4][4];
    for (int i = 0; i < 4; i++)
      for (int j = 0; j < 4; j++) acc[i][j] = (f32x4){0.f, 0.f, 0.f, 0.f};
    for (int ks = 0; ks < 2; ks++) {
      s8v af[4], bfv[4];
      for (int mi = 0; mi < 4; mi++) {   // A-operand = content rows
        int row = wr * 64 + mi * 16 + lr, cb = ks * 4 + lg;
        af[mi] = *(const s8v*)&As[row * 64 + (cb ^ (row & 7)) * 8];
      }
      for (int ni = 0; ni < 4; ni++) {   // B-operand = bucket rows
        int row = wc * 64 + ni * 16 + lr, cb = ks * 4 + lg;
        bfv[ni] = *(const s8v*)&Bs[row * 64 + (cb ^ (row & 7)) * 8];
      }
      for (int mi = 0; mi < 4; mi++)
        for (int ni = 0; ni < 4; ni++)
          acc[mi][ni] = __builtin_amdgcn_mfma_f32_16x16x32_bf16(
              af[mi], bfv[ni], acc[mi][ni], 0, 0, 0);
    }
    size_t base = (size_t)(b * 16 + h) * 1024;
    for (int mi = 0; mi < 4; mi++)
      for (int ni = 0; ni < 4; ni++)
        for (int r = 0; r < 4; r++) {
          int m = mrow + wr * 64 + mi * 16 + lg * 4 + r;   // content row
          int nn = ncol + wc * 64 + ni * 16 + lr;          // bucket col
          float v = acc[mi][ni][r];
          if (which == 1) v += mbias[b * 1024 + m];
          Out[(base + m) * 512 + nn] = (short)f2bf(v);
        }
  } else {
    short* TL = sh;   // 64*72 elems
    int idx = ((blockIdx.z - 64) * 8 + blockIdx.y) * 4 + blockIdx.x;  // 0..511
    int b = idx >> 8, h = (idx >> 4) & 15, lt = idx & 15;
    for (int i = 0; i < 2; i++) {
      int n = i * 256 + tid;
      int l = n >> 3, c = n & 7;
      s8v v = *(const s8v*)&Vc[(size_t)(b * 1024 + lt * 64 + l) * 1024 + h * 64 + c * 8];
      *(s8v*)&TL[l * 72 + c * 8] = v;
    }
    __syncthreads();
    for (int i = 0; i < 2; i++) {
      int m = i * 256 + tid;
      int d = m >> 3, c = m & 7;
      s8v o;
      for (int jj = 0; jj < 8; jj++) o[jj] = TL[(c * 8 + jj) * 72 + d];
      *(s8v*)&Vt[((size_t)(b * 16 + h) * 64 + d) * 1024 + lt * 64 + c * 8] = o;
    }
  }
}

// ---------------------------------------------------------------------------
// bias_build: block = one 64x64 (q,k) tile of one (b,h). Materializes
//   bias[q,k] = c2p[q][T[q-k]] + p2c[k][T[q-k]]  (mask already in p2c)
//   in MFMA FRAGMENT ORDER so attn reads it with 2 coalesced dwordx4/lane.
//   Also zeroes the attn split-K arrival counters (runs strictly before attn).
// ---------------------------------------------------------------------------
__global__ __launch_bounds__(256) void bias_build(
    const short* __restrict__ c2p, const short* __restrict__ p2c,
    const short* __restrict__ Tt, short* __restrict__ bias,
    int* __restrict__ cnt) {
  __shared__ short Wc[64 * 66];
  __shared__ short Wp[64 * 66];
  __shared__ short Tl[128];
  int tid = threadIdx.x;
  int wid = tid >> 6, lane = tid & 63;
  int lr = lane & 15, lg = lane >> 4;
  int qt = blockIdx.x, kt = blockIdx.y, bh = blockIdx.z;
  if (kt == 0 && tid == 0) cnt[bh * 16 + qt] = 0;   // pair = (b*16+h)*16+qt
  int q0 = qt * 64, k0 = kt * 64;
  int relbase = q0 - k0;
  size_t bh1024 = (size_t)bh * 1024;

  // Tl[i] = T[relbase - 63 + i], i in [0,126]; Tt index = rel + 1023
  if (tid < 127) Tl[tid] = Tt[relbase + 960 + tid];
  __syncthreads();

#pragma unroll
  for (int ii = 0; ii < 16; ii++) {
    int row = wid * 16 + ii;                 // uniform within wave
    int w0 = Tl[row];                        // window base for c2p row
    int col = w0 + lane; col = col > 511 ? 511 : col;
    Wc[row * 66 + lane] = c2p[(bh1024 + q0 + row) * 512 + col];
    int w0p_ = Tl[63 - row];                 // window base for p2c row
    int colp = w0p_ + lane; colp = colp > 511 ? 511 : colp;
    Wp[row * 66 + lane] = p2c[(bh1024 + k0 + row) * 512 + colp];
  }
  __syncthreads();

  int w0c[4], w0p[4];
#pragma unroll
  for (int r = 0; r < 4; r++) w0c[r] = Tl[wid * 16 + lg * 4 + r];
#pragma unroll
  for (int n = 0; n < 4; n++) w0p[n] = Tl[63 - (n * 16 + lr)];

  s8v o0, o1;
#pragma unroll
  for (int n = 0; n < 4; n++)
#pragma unroll
    for (int r = 0; r < 4; r++) {
      int qq = wid * 16 + lg * 4 + r;
      int kk = n * 16 + lr;
      int p = Tl[qq - kk + 63];
      float v = bf2f((unsigned short)Wc[qq * 66 + p - w0c[r]]) +
                bf2f((unsigned short)Wp[kk * 66 + p - w0p[n]]);
      short s = (short)f2bf(v);
      if (n < 2) o0[(n & 1) * 4 + r] = s; else o1[(n & 1) * 4 + r] = s;
    }
  size_t tile = ((size_t)bh * 16 + qt) * 16 + kt;
  size_t base = (tile * 4 + wid) * 1024 + lane * 8;
  *(s8v*)&bias[base] = o0;
  *(s8v*)&bias[base + 512] = o1;
}

// ---------------------------------------------------------------------------
// attn_frag: double-buffered skeleton, bias read as 2 coalesced
//   fragment-ordered loads per tile (prefetched one tile ahead).
//   NSPLIT=2 + FUSED COMBINE: partner blocks write partials, atomic arrival
//   counter; second arriver sums (fixed ks order -> bit-deterministic),
//   normalizes, writes out. No separate combine kernel.
// ---------------------------------------------------------------------------
template <int NSPLIT>
__global__ __launch_bounds__(256) void attn_frag(
    const short* __restrict__ Qc, const short* __restrict__ Kc,
    const short* __restrict__ Vt, const short* __restrict__ bias,
    float* __restrict__ Opart, float* __restrict__ dpart,
    int* __restrict__ cnt, float* __restrict__ out) {
  const int KSEG = 1024 / NSPLIT;
  const int NT = KSEG / 64;
  __shared__ short Kl[2][64 * 64];
  __shared__ short Vl[2][64 * 64];
  __shared__ short Pl[4][16 * 72];
  int tid = threadIdx.x;
  int wid = tid >> 6, lane = tid & 63;
  int lr = lane & 15, lg = lane >> 4;
  int qt = blockIdx.x, h = blockIdx.y, z = blockIdx.z;
  int b = (NSPLIT == 1) ? z : (z / NSPLIT);
  int ks = (NSPLIT == 1) ? 0 : (z % NSPLIT);
  int k0seg = ks * KSEG;
  int q0 = qt * 64, qbase = q0 + wid * 16;

  // Q fragments (held in registers for the whole kernel)
  s8v aq[2];
  for (int s_ = 0; s_ < 2; s_++)
    aq[s_] = *(const s8v*)&Qc[(size_t)(b * 1024 + qbase + lr) * 1024 + h * 64 + s_ * 32 + lg * 8];

  f32x4 oacc[4];
  for (int n = 0; n < 4; n++) oacc[n] = (f32x4){0.f, 0.f, 0.f, 0.f};
  float dsum[4] = {0.f, 0.f, 0.f, 0.f};

  auto stage = [&](int t, int buf) {
#pragma unroll
    for (int i = 0; i < 2; i++) {
      int n = i * 256 + tid;
      int row = n >> 3, cswz = n & 7, cb = cswz ^ (row & 7);
      gload_lds16(&Kc[(size_t)(b * 1024 + k0seg + t * 64 + row) * 1024 + h * 64 + cb * 8],
                  &Kl[buf][(i * 256 + wid * 64) * 8]);
      gload_lds16(&Vt[((size_t)(b * 16 + h) * 64 + row) * 1024 + k0seg + t * 64 + cb * 8],
                  &Vl[buf][(i * 256 + wid * 64) * 8]);
    }
  };
  auto fload = [&](int t, s8v& f0, s8v& f1) {
    size_t tile = (((size_t)(b * 16 + h) * 16 + qt) * 16 + (k0seg >> 6) + t);
    size_t base = (tile * 4 + wid) * 1024 + lane * 8;
    f0 = *(const s8v*)&bias[base];
    f1 = *(const s8v*)&bias[base + 512];
  };

  s8v fb0, fb1, fn0, fn1;
  stage(0, 0);
  fload(0, fb0, fb1);
  __syncthreads();   // drains stage(0)+fload(0)

#pragma unroll
  for (int t = 0; t < NT; ++t) {
    const int cur = t & 1, nxt = cur ^ 1;

    // A) issue next tile's async loads FIRST — overlap this tile's compute
    if (t + 1 < NT) {
      stage(t + 1, nxt);
      fload(t + 1, fn0, fn1);
    }

    // B) S = Q . K^T  (wave: 16 q x 64 k) from Kl[cur]
    f32x4 sacc[4];
#pragma unroll
    for (int n = 0; n < 4; n++) sacc[n] = (f32x4){0.f, 0.f, 0.f, 0.f};
#pragma unroll
    for (int s_ = 0; s_ < 2; s_++)
#pragma unroll
      for (int n = 0; n < 4; n++) {
        int row = n * 16 + lr, cb = s_ * 4 + lg, cbs = cb ^ (row & 7);
        s8v bk_ = *(const s8v*)&Kl[cur][row * 64 + cbs * 8];
        sacc[n] = __builtin_amdgcn_mfma_f32_16x16x32_bf16(aq[s_], bk_, sacc[n], 0, 0, 0);
      }

    // C) add fragment bias (registers), exp, write P
#pragma unroll
    for (int n = 0; n < 4; n++)
#pragma unroll
      for (int r = 0; r < 4; r++) {
        unsigned short bv_ = (unsigned short)((n < 2 ? fb0 : fb1)[(n & 1) * 4 + r]);
        float p = __expf(sacc[n][r] + bf2f(bv_));
        dsum[r] += p;
        Pl[wid][(lg * 4 + r) * 72 + n * 16 + lr] = (short)f2bf(p);
      }
    asm volatile("s_waitcnt lgkmcnt(0)" ::: "memory");

    // D) O += P . Vt^T  (wave: 16 q x 64 d) from Vl[cur]
#pragma unroll
    for (int s_ = 0; s_ < 2; s_++) {
      s8v ap = *(const s8v*)&Pl[wid][lr * 72 + s_ * 32 + lg * 8];
#pragma unroll
      for (int n = 0; n < 4; n++) {
        int row = n * 16 + lr, cb = s_ * 4 + lg, cbs = cb ^ (row & 7);
        s8v bv_ = *(const s8v*)&Vl[cur][row * 64 + cbs * 8];
        oacc[n] = __builtin_amdgcn_mfma_f32_16x16x32_bf16(ap, bv_, oacc[n], 0, 0, 0);
      }
    }

    // E) single barrier per tile
    __syncthreads();

    // F) rotate prefetched fragments
    if (t + 1 < NT) { fb0 = fn0; fb1 = fn1; }
  }

  for (int m = 1; m < 16; m <<= 1)
    for (int r = 0; r < 4; r++) dsum[r] += __shfl_xor(dsum[r], m, 64);

  if (NSPLIT == 1) {
    for (int n = 0; n < 4; n++)
      for (int r = 0; r < 4; r++) {
        int q = qbase + lg * 4 + r;
        int d = n * 16 + lr;
        out[(size_t)(b * 1024 + q) * 1024 + h * 64 + d] = oacc[n][r] / dsum[r];
      }
  } else {
    // --- write own partial ---
    size_t po = ((size_t)(z * 16 + h)) * 65536;
    for (int n = 0; n < 4; n++)
      for (int r = 0; r < 4; r++) {
        int q = qbase + lg * 4 + r;
        Opart[po + (size_t)q * 64 + n * 16 + lr] = oacc[n][r];
      }
    if (lr == 0)
      for (int r = 0; r < 4; r++)
        dpart[(z * 16 + h) * 1024 + qbase + lg * 4 + r] = dsum[r];

    // --- arrival counter: second arriver combines + writes out ---
    __shared__ int amFinal;
    __syncthreads();                       // all partial stores issued
    if (tid == 0) {
      __threadfence();                     // release: partials visible device-wide
      int pair = (b * 16 + h) * 16 + qt;
      int prev = atomicAdd(&cnt[pair], 1); // device-scope by default
      amFinal = (prev == 1);
    }
    __syncthreads();
    if (amFinal) {
      __threadfence();                     // acquire side
      int zp = b * NSPLIT + (ks ^ 1);      // partner
      size_t pp = ((size_t)(zp * 16 + h)) * 65536;
      // fixed summation order (ks=0 partial + ks=1 partial) -> deterministic
      for (int n = 0; n < 4; n++)
        for (int r = 0; r < 4; r++) {
          int q = qbase + lg * 4 + r;
          oacc[n][r] += Opart[pp + (size_t)q * 64 + n * 16 + lr];
        }
      float dtot[4];
      for (int r = 0; r < 4; r++) {
        int q = qbase + lg * 4 + r;
        dtot[r] = dsum[r] + dpart[(zp * 16 + h) * 1024 + q];
      }
      for (int n = 0; n < 4; n++)
        for (int r = 0; r < 4; r++) {
          int q = qbase + lg * 4 + r;
          out[(size_t)(b * 1024 + q) * 1024 + h * 64 + n * 16 + lr] =
              oacc[n][r] / dtot[r];
        }
    }
  }
}

// ---------------------------------------------------------------------------
// attn_gather: fallback (used only if workspace too small for bias_frag)
// ---------------------------------------------------------------------------
template <int NSPLIT>
__global__ __launch_bounds__(256) void attn_gather(
    const short* __restrict__ Qc, const short* __restrict__ Kc,
    const short* __restrict__ Vt, const short* __restrict__ c2p,
    const short* __restrict__ p2c, const short* __restrict__ Tt,
    float* __restrict__ Opart, float* __restrict__ dpart,
    float* __restrict__ out) {
  const int KSEG = 1024 / NSPLIT;
  const int NT = KSEG / 64;
  const int TLN = 64 + KSEG - 1;
  __shared__ short Kl[2][64 * 64];
  __shared__ short Vl[2][64 * 64];
  __shared__ short Pl[4][16 * 72];
  __shared__ short Tl[TLN + 1];
  int tid = threadIdx.x;
  int wid = tid >> 6, lane = tid & 63;
  int lr = lane & 15, lg = lane >> 4;
  int qt = blockIdx.x, h = blockIdx.y, z = blockIdx.z;
  int b = (NSPLIT == 1) ? z : (z / NSPLIT);
  int ks = (NSPLIT == 1) ? 0 : (z % NSPLIT);
  int k0seg = ks * KSEG;
  int q0 = qt * 64, qbase = q0 + wid * 16;
  size_t bh1024 = (size_t)(b * 16 + h) * 1024;

  for (int i = tid; i < TLN; i += 256) Tl[i] = Tt[(q0 - k0seg - (KSEG - 1) + 1023) + i];

  s8v aq[2];
  for (int s_ = 0; s_ < 2; s_++)
    aq[s_] = *(const s8v*)&Qc[(size_t)(b * 1024 + qbase + lr) * 1024 + h * 64 + s_ * 32 + lg * 8];

  f32x4 oacc[4];
  for (int n = 0; n < 4; n++) oacc[n] = (f32x4){0.f, 0.f, 0.f, 0.f};
  float dsum[4] = {0.f, 0.f, 0.f, 0.f};
  __syncthreads();

  auto stage = [&](int t, int buf) {
#pragma unroll
    for (int i = 0; i < 2; i++) {
      int n = i * 256 + tid;
      int row = n >> 3, cswz = n & 7, cb = cswz ^ (row & 7);
      gload_lds16(&Kc[(size_t)(b * 1024 + k0seg + t * 64 + row) * 1024 + h * 64 + cb * 8],
                  &Kl[buf][(i * 256 + wid * 64) * 8]);
      gload_lds16(&Vt[((size_t)(b * 16 + h) * 64 + row) * 1024 + k0seg + t * 64 + cb * 8],
                  &Vl[buf][(i * 256 + wid * 64) * 8]);
    }
  };
  auto gather = [&](int t, unsigned short* cg, unsigned short* pg) {
#pragma unroll
    for (int n = 0; n < 4; n++) {
      int k = k0seg + t * 64 + n * 16 + lr;
      size_t prow = (bh1024 + k) * 512;
      int jb = wid * 16 - t * 64 - lr + (KSEG - 1) - n * 16 + lg * 4;
#pragma unroll
      for (int r = 0; r < 4; r++) {
        int q = qbase + lg * 4 + r;
        int idx = Tl[jb + r];
        cg[n * 4 + r] = (unsigned short)c2p[(bh1024 + q) * 512 + idx];
        pg[n * 4 + r] = (unsigned short)p2c[prow + idx];
      }
    }
  };

  unsigned short c2g[16], p2g[16], c2n[16], p2n[16];
  stage(0, 0);
  gather(0, c2g, p2g);
  __syncthreads();

#pragma unroll
  for (int t = 0; t < NT; ++t) {
    const int cur = t & 1, nxt = cur ^ 1;
    if (t + 1 < NT) { stage(t + 1, nxt); gather(t + 1, c2n, p2n); }

    f32x4 sacc[4];
#pragma unroll
    for (int n = 0; n < 4; n++) sacc[n] = (f32x4){0.f, 0.f, 0.f, 0.f};
#pragma unroll
    for (int s_ = 0; s_ < 2; s_++)
#pragma unroll
      for (int n = 0; n < 4; n++) {
        int row = n * 16 + lr, cb = s_ * 4 + lg, cbs = cb ^ (row & 7);
        s8v bk_ = *(const s8v*)&Kl[cur][row * 64 + cbs * 8];
        sacc[n] = __builtin_amdgcn_mfma_f32_16x16x32_bf16(aq[s_], bk_, sacc[n], 0, 0, 0);
      }
#pragma unroll
    for (int n = 0; n < 4; n++)
#pragma unroll
      for (int r = 0; r < 4; r++) {
        float bias = bf2f(c2g[n * 4 + r]) + bf2f(p2g[n * 4 + r]);
        float p = __expf(sacc[n][r] + bias);
        dsum[r] += p;
        Pl[wid][(lg * 4 + r) * 72 + n * 16 + lr] = (short)f2bf(p);
      }
    asm volatile("s_waitcnt lgkmcnt(0)" ::: "memory");
#pragma unroll
    for (int s_ = 0; s_ < 2; s_++) {
      s8v ap = *(const s8v*)&Pl[wid][lr * 72 + s_ * 32 + lg * 8];
#pragma unroll
      for (int n = 0; n < 4; n++) {
        int row = n * 16 + lr, cb = s_ * 4 + lg, cbs = cb ^ (row & 7);
        s8v bv_ = *(const s8v*)&Vl[cur][row * 64 + cbs * 8];
        oacc[n] = __builtin_amdgcn_mfma_f32_16x16x32_bf16(ap, bv_, oacc[n], 0, 0, 0);
      }
    }
    __syncthreads();
    if (t + 1 < NT) {
#pragma unroll
      for (int i = 0; i < 16; i++) { c2g[i] = c2n[i]; p2g[i] = p2n[i]; }
    }
  }

  for (int m = 1; m < 16; m <<= 1)
    for (int r = 0; r < 4; r++) dsum[r] += __shfl_xor(dsum[r], m, 64);

  if (NSPLIT == 1) {
    for (int n = 0; n < 4; n++)
      for (int r = 0; r < 4; r++) {
        int q = qbase + lg * 4 + r;
        int d = n * 16 + lr;
        out[(size_t)(b * 1024 + q) * 1024 + h * 64 + d] = oacc[n][r] / dsum[r];
      }
  } else {
    size_t po = ((size_t)(z * 16 + h)) * 65536;
    for (int n = 0; n < 4; n++)
      for (int r = 0; r < 4; r++) {
        int q = qbase + lg * 4 + r;
        Opart[po + (size_t)q * 64 + n * 16 + lr] = oacc[n][r];
      }
    if (lr == 0)
      for (int r = 0; r < 4; r++)
        dpart[(z * 16 + h) * 1024 + qbase + lg * 4 + r] = dsum[r];
  }
}

// ---------------------------------------------------------------------------
// combine: out = sum_ks Opart / sum_ks dpart  (fallback path only)
// ---------------------------------------------------------------------------
template <int NSPLIT>
__global__ __launch_bounds__(256) void combine_kernel(
    const float* __restrict__ Opart, const float* __restrict__ dpart,
    float* __restrict__ out) {
  int idx = blockIdx.x * 256 + threadIdx.x;
  int pos = idx * 4;                 // flat out index, 4 floats per thread
  int b = pos >> 20;
  int q = (pos >> 10) & 1023;
  int hd = pos & 1023;
  int h = hd >> 6, d = hd & 63;
  f4v s = (f4v){0.f, 0.f, 0.f, 0.f};
  float dn = 0.f;
  for (int ks = 0; ks < NSPLIT; ks++) {
    int zh = (b * NSPLIT + ks) * 16 + h;
    s += *(const f4v*)&Opart[(size_t)zh * 65536 + q * 64 + d];
    dn += dpart[zh * 1024 + q];
  }
  f4v r = s / dn;
  *(f4v*)&out[pos] = r;
}

// ---------------------------------------------------------------------------
extern "C" void kernel_launch(void* const* d_in, const int* in_sizes, int n_in,
                              void* d_out, int out_size, void* d_ws, size_t ws_size,
                              hipStream_t stream) {
  (void)in_sizes; (void)n_in; (void)out_size;
  const float* hidden = (const float*)d_in[0];
  const int* mask = (const int*)d_in[1];
  const float* rel = (const float*)d_in[2];
  const float* Wq = (const float*)d_in[3];
  const float* bq = (const float*)d_in[4];
  const float* Wk = (const float*)d_in[5];
  const float* bk = (const float*)d_in[6];
  const float* Wv = (const float*)d_in[7];
  const float* bv = (const float*)d_in[8];
  float* out = (float*)d_out;

  char* w = (char*)d_ws;
  short* Abf = (short*)w; w += 2560 * 1024 * 2;          // 5.25 MB
  short* Wbf = (short*)w; w += 3 * 1024 * 1024 * 2;      // 6.29 MB
  short* Qc  = (short*)w; w += 2560 * 1024 * 2;
  short* Kc  = (short*)w; w += 2560 * 1024 * 2;
  short* Vc  = (short*)w; w += 2560 * 1024 * 2;
  short* Vt  = (short*)w; w += 2 * 16 * 64 * 1024 * 2;   // 4.19 MB
  short* c2p = (short*)w; w += (size_t)2 * 16 * 1024 * 512 * 2;  // 33.5 MB
  short* p2c = (short*)w; w += (size_t)2 * 16 * 1024 * 512 * 2;  // 33.5 MB
  short* Tt  = (short*)w; w += 4096;
  float* mbias = (float*)w; w += 8192;
  // frag path: bias matrix + counters appended; Opart/dpart overlay c2p/p2c
  // (dead after bias_build; attn writes Opart only after bias_build done).
  short* bias_frag = (short*)w;
  int* cnt = (int*)(w + (size_t)8192 * 4096 * 2);
  size_t need_frag = (size_t)(w - (char*)d_ws) + (size_t)8192 * 4096 * 2 + 4096;
  // gather path: Opart/dpart appended (c2p/p2c stay live through attn).
  float* Opart_old = (float*)w;
  size_t need_old = (size_t)(w - (char*)d_ws) + (size_t)8 * 16 * 1024 * 64 * 4 + 8 * 16 * 1024 * 4;

  prep_kernel<<<5648, 256, 0, stream>>>(hidden, rel, Wq, Wk, Wv, mask, Abf, Wbf, mbias, Tt);
  gemm_qkv<<<dim3(8, 20, 3), 256, 0, stream>>>(Abf, Wbf, bq, bk, bv, Qc, Kc, Vc);
  pos_trans<<<dim3(4, 8, 80), 256, 0, stream>>>(Qc, Kc, Vc, mbias, c2p, p2c, Vt);

  if (ws_size >= need_frag) {
    float* Opart = (float*)c2p;     // 16.8 MB needed, 33.5 MB region
    float* dpart = (float*)p2c;     // 256 KB into p2c region
    bias_build<<<dim3(16, 16, 32), 256, 0, stream>>>(c2p, p2c, Tt, bias_frag, cnt);
    attn_frag<2><<<dim3(16, 16, 4), 256, 0, stream>>>(Qc, Kc, Vt, bias_frag,
                                                      Opart, dpart, cnt, out);
  } else if (ws_size >= need_old) {
    float* Opart = Opart_old;
    float* dpart = (float*)((char*)Opart_old + (size_t)8 * 16 * 1024 * 64 * 4);
    attn_gather<4><<<dim3(16, 16, 8), 256, 0, stream>>>(Qc, Kc, Vt, c2p, p2c, Tt,
                                                        Opart, dpart, out);
    combine_kernel<4><<<2048, 256, 0, stream>>>(Opart, dpart, out);
  } else {
    attn_gather<1><<<dim3(16, 16, 2), 256, 0, stream>>>(Qc, Kc, Vt, c2p, p2c, Tt,
                                                        (float*)Opart_old, (float*)Opart_old, out);
  }
}

// Round 13
// 136.577 us; speedup vs baseline: 1.6331x; 1.6331x over previous
//
#include <hip/hip_runtime.h>

// ---------------------------------------------------------------------------
// DeBERTa-v2 disentangled self-attention, MI355X (gfx950)
// B=2, L=1024, D=1024, H=16, HEAD=64, ATT_SPAN=256 (pos dim 512), scale=sqrt(192)
// ---------------------------------------------------------------------------

typedef short s8v __attribute__((ext_vector_type(8)));
typedef short s4v __attribute__((ext_vector_type(4)));
typedef float f32x4 __attribute__((ext_vector_type(4)));
typedef float f4v __attribute__((ext_vector_type(4)));

#define QK_SCALE 0.26864243f   // 192^(-1/4); folded so all score terms get /sqrt(192)

__device__ __forceinline__ unsigned short f2bf(float f) {
  unsigned u = __builtin_bit_cast(unsigned, f);
  u += 0x7fffu + ((u >> 16) & 1u);          // RNE
  return (unsigned short)(u >> 16);
}
__device__ __forceinline__ float bf2f(unsigned short h) {
  unsigned u = ((unsigned)h) << 16;
  return __builtin_bit_cast(float, u);
}

__device__ __forceinline__ void gload_lds16(const void* g, void* l) {
  __builtin_amdgcn_global_load_lds(
      (const __attribute__((address_space(1))) void*)g,
      (__attribute__((address_space(3))) void*)l, 16, 0, 0);
}

// ---------------------------------------------------------------------------
// prep: f32->bf16 conversions, bucket table, mask bias
// ---------------------------------------------------------------------------
__global__ __launch_bounds__(256) void prep_kernel(
    const float* __restrict__ hidden, const float* __restrict__ rel,
    const float* __restrict__ Wq, const float* __restrict__ Wk,
    const float* __restrict__ Wv, const int* __restrict__ mask,
    short* __restrict__ Abf, short* __restrict__ Wbf,
    float* __restrict__ mbias, short* __restrict__ Tt) {
  int idx = blockIdx.x * 256 + threadIdx.x;
  const int NCONV = 1441792;  // (2560*1024 + 3*1024*1024)/4 float4s
  if (idx < NCONV) {
    const float* src; short* dst; int off;
    if (idx < 524288) { src = hidden; dst = Abf; off = idx; }
    else if (idx < 655360) { src = rel; dst = Abf + 2048 * 1024; off = idx - 524288; }
    else {
      int j = idx - 655360;
      int w = j / 262144; off = j - w * 262144;
      src = (w == 0) ? Wq : (w == 1) ? Wk : Wv;
      dst = Wbf + w * 1048576;
    }
    f4v v = ((const f4v*)src)[off];
    s4v o;
    o[0] = (short)f2bf(v[0]); o[1] = (short)f2bf(v[1]);
    o[2] = (short)f2bf(v[2]); o[3] = (short)f2bf(v[3]);
    ((s4v*)dst)[off] = o;
  } else {
    int j = idx - NCONV;
    if (j < 2047) {
      int r = j - 1023;
      float fr = (float)r;
      float sign = (r > 0) ? 1.f : ((r < 0) ? -1.f : 0.f);
      float abs_pos = (r < 128 && r > -128) ? 127.f : fabsf(fr);
      const float logc = 1.3843393245589053f;  // f32(log(511/128))
      float log_pos = ceilf(logf(abs_pos * (1.f / 128.f)) / logc * 127.f) + 128.f;
      float bucket = (abs_pos <= 128.f) ? fr : log_pos * sign;
      int bi = (int)bucket + 256;
      bi = bi < 0 ? 0 : (bi > 511 ? 511 : bi);
      Tt[j] = (short)bi;
    } else if (j < 4095) {
      int m = j - 2047;
      mbias[m] = (mask[m] > 0) ? 0.f : -1e9f;
    }
  }
}

// ---------------------------------------------------------------------------
// gemm_qkv: C[m,n] = (sum_k A[m,k]*W[n,k] + bias[n]) * scale, bf16 out
//   128x128 tile, XOR-SWIZZLED LDS (R9: conflicts 8.26M -> fixed).
//   z==2 (V): position rows (>=2048) never consumed -> early exit.
// ---------------------------------------------------------------------------
__global__ __launch_bounds__(256) void gemm_qkv(
    const short* __restrict__ Abf, const short* __restrict__ Wbf,
    const float* __restrict__ bq, const float* __restrict__ bk,
    const float* __restrict__ bv,
    short* __restrict__ Qc, short* __restrict__ Kc, short* __restrict__ Vc) {
  __shared__ short As[128 * 64];
  __shared__ short Bs[128 * 64];
  int tid = threadIdx.x;
  int wid = tid >> 6, lane = tid & 63;
  int lr = lane & 15, lg = lane >> 4;
  int wr = wid >> 1, wc = wid & 1;
  int z = blockIdx.z;
  int brow = blockIdx.y * 128;
  if (z == 2 && brow >= 2048) return;   // V pos-rows unused
  const short* W = Wbf + z * 1048576;
  const float* bias = (z == 0) ? bq : (z == 1) ? bk : bv;
  short* C = (z == 0) ? Qc : (z == 1) ? Kc : Vc;
  float scale = (z == 2) ? 1.f : QK_SCALE;
  int bcol = blockIdx.x * 128;

  f32x4 acc[4][4];
  for (int i = 0; i < 4; i++)
    for (int j = 0; j < 4; j++) acc[i][j] = (f32x4){0.f, 0.f, 0.f, 0.f};

  for (int k0 = 0; k0 < 1024; k0 += 64) {
    for (int i = 0; i < 4; i++) {
      int n = i * 256 + wid * 64 + lane;
      int row = n >> 3, cswz = n & 7, cb = cswz ^ (row & 7);
      const short* gA = Abf + (size_t)(brow + row) * 1024 + k0 + cb * 8;
      gload_lds16(gA, &As[(i * 256 + wid * 64) * 8]);
      const short* gB = W + (size_t)(bcol + row) * 1024 + k0 + cb * 8;
      gload_lds16(gB, &Bs[(i * 256 + wid * 64) * 8]);
    }
    __syncthreads();
    for (int ks = 0; ks < 2; ks++) {
      s8v af[4], bfv[4];
      for (int mi = 0; mi < 4; mi++) {
        int row = wr * 64 + mi * 16 + lr, cb = ks * 4 + lg;
        af[mi] = *(const s8v*)&As[row * 64 + (cb ^ (row & 7)) * 8];
      }
      for (int ni = 0; ni < 4; ni++) {
        int row = wc * 64 + ni * 16 + lr, cb = ks * 4 + lg;
        bfv[ni] = *(const s8v*)&Bs[row * 64 + (cb ^ (row & 7)) * 8];
      }
      for (int mi = 0; mi < 4; mi++)
        for (int ni = 0; ni < 4; ni++)
          acc[mi][ni] = __builtin_amdgcn_mfma_f32_16x16x32_bf16(
              af[mi], bfv[ni], acc[mi][ni], 0, 0, 0);
    }
    __syncthreads();
  }
  for (int mi = 0; mi < 4; mi++)
    for (int ni = 0; ni < 4; ni++) {
      int col = bcol + wc * 64 + ni * 16 + lr;
      float bb = bias[col];
      for (int r = 0; r < 4; r++) {
        int row = brow + wr * 64 + mi * 16 + lg * 4 + r;
        float v = (acc[mi][ni][r] + bb) * scale;
        C[(size_t)row * 1024 + col] = (short)f2bf(v);
      }
    }
}

// ---------------------------------------------------------------------------
// pos_trans: MERGED pos_gemm (z<64) + transpose_v (z>=64).
//   pos part XOR-SWIZZLED (same fix as gemm_qkv R9; linear [row][64] LDS
//   fragment reads are a 16-way ds_read_b128 bank conflict).
//   pos part:  which=0: c2p[bh][q][p] = Q[q].posK[p]
//              which=1: p2c[bh][k][p] = K[k].posQ[p] + mbias[b,k]
//   trans part: Vt[b,h,d,l] = Vc[b*1024+l, h*64+d]
// ---------------------------------------------------------------------------
__global__ __launch_bounds__(256) void pos_trans(
    const short* __restrict__ Qc, const short* __restrict__ Kc,
    const short* __restrict__ Vc, const float* __restrict__ mbias,
    short* __restrict__ c2p, short* __restrict__ p2c,
    short* __restrict__ Vt) {
  __shared__ short sh[2 * 128 * 64];
  int tid = threadIdx.x;
  if (blockIdx.z < 64) {
    short* As = sh;
    short* Bs = sh + 128 * 64;
    int wid = tid >> 6, lane = tid & 63;
    int lr = lane & 15, lg = lane >> 4;
    int wr = wid >> 1, wc = wid & 1;
    int zz = blockIdx.z;       // 0..63
    int which = zz >> 5;
    int bh = zz & 31;
    int b = bh >> 4, h = bh & 15;
    const short* Arows = (which == 0) ? Qc : Kc;   // content source
    const short* Brows = (which == 0) ? Kc : Qc;   // pos-projection source
    short* Out = (which == 0) ? c2p : p2c;
    int mrow = blockIdx.y * 128;   // content base (1024/128 = 8)
    int ncol = blockIdx.x * 128;   // bucket base  (512/128 = 4)

    for (int i = 0; i < 4; i++) {
      int n = i * 256 + wid * 64 + lane;
      int row = n >> 3, cswz = n & 7, cb = cswz ^ (row & 7);
      const short* gA = Arows + (size_t)(b * 1024 + mrow + row) * 1024 + h * 64 + cb * 8;
      gload_lds16(gA, &As[(i * 256 + wid * 64) * 8]);
      const short* gB = Brows + (size_t)(2048 + ncol + row) * 1024 + h * 64 + cb * 8;
      gload_lds16(gB, &Bs[(i * 256 + wid * 64) * 8]);
    }
    __syncthreads();

    f32x4 acc[4][4];
    for (int i = 0; i < 4; i++)
      for (int j = 0; j < 4; j++) acc[i][j] = (f32x4){0.f, 0.f, 0.f, 0.f};
    for (int ks = 0; ks < 2; ks++) {
      s8v af[4], bfv[4];
      for (int mi = 0; mi < 4; mi++) {   // A-operand = content rows
        int row = wr * 64 + mi * 16 + lr, cb = ks * 4 + lg;
        af[mi] = *(const s8v*)&As[row * 64 + (cb ^ (row & 7)) * 8];
      }
      for (int ni = 0; ni < 4; ni++) {   // B-operand = bucket rows
        int row = wc * 64 + ni * 16 + lr, cb = ks * 4 + lg;
        bfv[ni] = *(const s8v*)&Bs[row * 64 + (cb ^ (row & 7)) * 8];
      }
      for (int mi = 0; mi < 4; mi++)
        for (int ni = 0; ni < 4; ni++)
          acc[mi][ni] = __builtin_amdgcn_mfma_f32_16x16x32_bf16(
              af[mi], bfv[ni], acc[mi][ni], 0, 0, 0);
    }
    size_t base = (size_t)(b * 16 + h) * 1024;
    for (int mi = 0; mi < 4; mi++)
      for (int ni = 0; ni < 4; ni++)
        for (int r = 0; r < 4; r++) {
          int m = mrow + wr * 64 + mi * 16 + lg * 4 + r;   // content row
          int nn = ncol + wc * 64 + ni * 16 + lr;          // bucket col
          float v = acc[mi][ni][r];
          if (which == 1) v += mbias[b * 1024 + m];
          Out[(base + m) * 512 + nn] = (short)f2bf(v);
        }
  } else {
    short* TL = sh;   // 64*72 elems
    int idx = ((blockIdx.z - 64) * 8 + blockIdx.y) * 4 + blockIdx.x;  // 0..511
    int b = idx >> 8, h = (idx >> 4) & 15, lt = idx & 15;
    for (int i = 0; i < 2; i++) {
      int n = i * 256 + tid;
      int l = n >> 3, c = n & 7;
      s8v v = *(const s8v*)&Vc[(size_t)(b * 1024 + lt * 64 + l) * 1024 + h * 64 + c * 8];
      *(s8v*)&TL[l * 72 + c * 8] = v;
    }
    __syncthreads();
    for (int i = 0; i < 2; i++) {
      int m = i * 256 + tid;
      int d = m >> 3, c = m & 7;
      s8v o;
      for (int jj = 0; jj < 8; jj++) o[jj] = TL[(c * 8 + jj) * 72 + d];
      *(s8v*)&Vt[((size_t)(b * 16 + h) * 64 + d) * 1024 + lt * 64 + c * 8] = o;
    }
  }
}

// ---------------------------------------------------------------------------
// bias_build: block = one 64x64 (q,k) tile of one (b,h). Materializes
//   bias[q,k] = c2p[q][T[q-k]] + p2c[k][T[q-k]]  (mask already in p2c)
//   in MFMA FRAGMENT ORDER so attn reads it with 2 coalesced dwordx4/lane.
// ---------------------------------------------------------------------------
__global__ __launch_bounds__(256) void bias_build(
    const short* __restrict__ c2p, const short* __restrict__ p2c,
    const short* __restrict__ Tt, short* __restrict__ bias) {
  __shared__ short Wc[64 * 66];
  __shared__ short Wp[64 * 66];
  __shared__ short Tl[128];
  int tid = threadIdx.x;
  int wid = tid >> 6, lane = tid & 63;
  int lr = lane & 15, lg = lane >> 4;
  int qt = blockIdx.x, kt = blockIdx.y, bh = blockIdx.z;
  int q0 = qt * 64, k0 = kt * 64;
  int relbase = q0 - k0;
  size_t bh1024 = (size_t)bh * 1024;

  // Tl[i] = T[relbase - 63 + i], i in [0,126]; Tt index = rel + 1023
  if (tid < 127) Tl[tid] = Tt[relbase + 960 + tid];
  __syncthreads();

#pragma unroll
  for (int ii = 0; ii < 16; ii++) {
    int row = wid * 16 + ii;                 // uniform within wave
    int w0 = Tl[row];                        // window base for c2p row
    int col = w0 + lane; col = col > 511 ? 511 : col;
    Wc[row * 66 + lane] = c2p[(bh1024 + q0 + row) * 512 + col];
    int w0p_ = Tl[63 - row];                 // window base for p2c row
    int colp = w0p_ + lane; colp = colp > 511 ? 511 : colp;
    Wp[row * 66 + lane] = p2c[(bh1024 + k0 + row) * 512 + colp];
  }
  __syncthreads();

  int w0c[4], w0p[4];
#pragma unroll
  for (int r = 0; r < 4; r++) w0c[r] = Tl[wid * 16 + lg * 4 + r];
#pragma unroll
  for (int n = 0; n < 4; n++) w0p[n] = Tl[63 - (n * 16 + lr)];

  s8v o0, o1;
#pragma unroll
  for (int n = 0; n < 4; n++)
#pragma unroll
    for (int r = 0; r < 4; r++) {
      int qq = wid * 16 + lg * 4 + r;
      int kk = n * 16 + lr;
      int p = Tl[qq - kk + 63];
      float v = bf2f((unsigned short)Wc[qq * 66 + p - w0c[r]]) +
                bf2f((unsigned short)Wp[kk * 66 + p - w0p[n]]);
      short s = (short)f2bf(v);
      if (n < 2) o0[(n & 1) * 4 + r] = s; else o1[(n & 1) * 4 + r] = s;
    }
  size_t tile = ((size_t)bh * 16 + qt) * 16 + kt;
  size_t base = (tile * 4 + wid) * 1024 + lane * 8;
  *(s8v*)&bias[base] = o0;
  *(s8v*)&bias[base + 512] = o1;
}

// ---------------------------------------------------------------------------
// attn_frag: double-buffered skeleton, bias read as 2 coalesced
//   fragment-ordered loads per tile (prefetched one tile ahead).
//   NSPLIT=2: K-split for occupancy; separate combine launch (R12 showed
//   fused combine via __threadfence thrashes per-XCD L2 -> 4x slowdown).
// ---------------------------------------------------------------------------
template <int NSPLIT>
__global__ __launch_bounds__(256) void attn_frag(
    const short* __restrict__ Qc, const short* __restrict__ Kc,
    const short* __restrict__ Vt, const short* __restrict__ bias,
    float* __restrict__ Opart, float* __restrict__ dpart,
    float* __restrict__ out) {
  const int KSEG = 1024 / NSPLIT;
  const int NT = KSEG / 64;
  __shared__ short Kl[2][64 * 64];
  __shared__ short Vl[2][64 * 64];
  __shared__ short Pl[4][16 * 72];
  int tid = threadIdx.x;
  int wid = tid >> 6, lane = tid & 63;
  int lr = lane & 15, lg = lane >> 4;
  int qt = blockIdx.x, h = blockIdx.y, z = blockIdx.z;
  int b = (NSPLIT == 1) ? z : (z / NSPLIT);
  int ks = (NSPLIT == 1) ? 0 : (z % NSPLIT);
  int k0seg = ks * KSEG;
  int q0 = qt * 64, qbase = q0 + wid * 16;

  // Q fragments (held in registers for the whole kernel)
  s8v aq[2];
  for (int s_ = 0; s_ < 2; s_++)
    aq[s_] = *(const s8v*)&Qc[(size_t)(b * 1024 + qbase + lr) * 1024 + h * 64 + s_ * 32 + lg * 8];

  f32x4 oacc[4];
  for (int n = 0; n < 4; n++) oacc[n] = (f32x4){0.f, 0.f, 0.f, 0.f};
  float dsum[4] = {0.f, 0.f, 0.f, 0.f};

  auto stage = [&](int t, int buf) {
#pragma unroll
    for (int i = 0; i < 2; i++) {
      int n = i * 256 + tid;
      int row = n >> 3, cswz = n & 7, cb = cswz ^ (row & 7);
      gload_lds16(&Kc[(size_t)(b * 1024 + k0seg + t * 64 + row) * 1024 + h * 64 + cb * 8],
                  &Kl[buf][(i * 256 + wid * 64) * 8]);
      gload_lds16(&Vt[((size_t)(b * 16 + h) * 64 + row) * 1024 + k0seg + t * 64 + cb * 8],
                  &Vl[buf][(i * 256 + wid * 64) * 8]);
    }
  };
  auto fload = [&](int t, s8v& f0, s8v& f1) {
    size_t tile = (((size_t)(b * 16 + h) * 16 + qt) * 16 + (k0seg >> 6) + t);
    size_t base = (tile * 4 + wid) * 1024 + lane * 8;
    f0 = *(const s8v*)&bias[base];
    f1 = *(const s8v*)&bias[base + 512];
  };

  s8v fb0, fb1, fn0, fn1;
  stage(0, 0);
  fload(0, fb0, fb1);
  __syncthreads();   // drains stage(0)+fload(0)

#pragma unroll
  for (int t = 0; t < NT; ++t) {
    const int cur = t & 1, nxt = cur ^ 1;

    // A) issue next tile's async loads FIRST — overlap this tile's compute
    if (t + 1 < NT) {
      stage(t + 1, nxt);
      fload(t + 1, fn0, fn1);
    }

    // B) S = Q . K^T  (wave: 16 q x 64 k) from Kl[cur]
    f32x4 sacc[4];
#pragma unroll
    for (int n = 0; n < 4; n++) sacc[n] = (f32x4){0.f, 0.f, 0.f, 0.f};
#pragma unroll
    for (int s_ = 0; s_ < 2; s_++)
#pragma unroll
      for (int n = 0; n < 4; n++) {
        int row = n * 16 + lr, cb = s_ * 4 + lg, cbs = cb ^ (row & 7);
        s8v bk_ = *(const s8v*)&Kl[cur][row * 64 + cbs * 8];
        sacc[n] = __builtin_amdgcn_mfma_f32_16x16x32_bf16(aq[s_], bk_, sacc[n], 0, 0, 0);
      }

    // C) add fragment bias (registers), exp, write P
#pragma unroll
    for (int n = 0; n < 4; n++)
#pragma unroll
      for (int r = 0; r < 4; r++) {
        unsigned short bv_ = (unsigned short)((n < 2 ? fb0 : fb1)[(n & 1) * 4 + r]);
        float p = __expf(sacc[n][r] + bf2f(bv_));
        dsum[r] += p;
        Pl[wid][(lg * 4 + r) * 72 + n * 16 + lr] = (short)f2bf(p);
      }
    asm volatile("s_waitcnt lgkmcnt(0)" ::: "memory");

    // D) O += P . Vt^T  (wave: 16 q x 64 d) from Vl[cur]
#pragma unroll
    for (int s_ = 0; s_ < 2; s_++) {
      s8v ap = *(const s8v*)&Pl[wid][lr * 72 + s_ * 32 + lg * 8];
#pragma unroll
      for (int n = 0; n < 4; n++) {
        int row = n * 16 + lr, cb = s_ * 4 + lg, cbs = cb ^ (row & 7);
        s8v bv_ = *(const s8v*)&Vl[cur][row * 64 + cbs * 8];
        oacc[n] = __builtin_amdgcn_mfma_f32_16x16x32_bf16(ap, bv_, oacc[n], 0, 0, 0);
      }
    }

    // E) single barrier per tile
    __syncthreads();

    // F) rotate prefetched fragments
    if (t + 1 < NT) { fb0 = fn0; fb1 = fn1; }
  }

  for (int m = 1; m < 16; m <<= 1)
    for (int r = 0; r < 4; r++) dsum[r] += __shfl_xor(dsum[r], m, 64);

  if (NSPLIT == 1) {
    for (int n = 0; n < 4; n++)
      for (int r = 0; r < 4; r++) {
        int q = qbase + lg * 4 + r;
        int d = n * 16 + lr;
        out[(size_t)(b * 1024 + q) * 1024 + h * 64 + d] = oacc[n][r] / dsum[r];
      }
  } else {
    size_t po = ((size_t)(z * 16 + h)) * 65536;
    for (int n = 0; n < 4; n++)
      for (int r = 0; r < 4; r++) {
        int q = qbase + lg * 4 + r;
        Opart[po + (size_t)q * 64 + n * 16 + lr] = oacc[n][r];
      }
    if (lr == 0)
      for (int r = 0; r < 4; r++)
        dpart[(z * 16 + h) * 1024 + qbase + lg * 4 + r] = dsum[r];
  }
}

// ---------------------------------------------------------------------------
// attn_gather: fallback (used only if workspace too small for bias_frag)
// ---------------------------------------------------------------------------
template <int NSPLIT>
__global__ __launch_bounds__(256) void attn_gather(
    const short* __restrict__ Qc, const short* __restrict__ Kc,
    const short* __restrict__ Vt, const short* __restrict__ c2p,
    const short* __restrict__ p2c, const short* __restrict__ Tt,
    float* __restrict__ Opart, float* __restrict__ dpart,
    float* __restrict__ out) {
  const int KSEG = 1024 / NSPLIT;
  const int NT = KSEG / 64;
  const int TLN = 64 + KSEG - 1;
  __shared__ short Kl[2][64 * 64];
  __shared__ short Vl[2][64 * 64];
  __shared__ short Pl[4][16 * 72];
  __shared__ short Tl[TLN + 1];
  int tid = threadIdx.x;
  int wid = tid >> 6, lane = tid & 63;
  int lr = lane & 15, lg = lane >> 4;
  int qt = blockIdx.x, h = blockIdx.y, z = blockIdx.z;
  int b = (NSPLIT == 1) ? z : (z / NSPLIT);
  int ks = (NSPLIT == 1) ? 0 : (z % NSPLIT);
  int k0seg = ks * KSEG;
  int q0 = qt * 64, qbase = q0 + wid * 16;
  size_t bh1024 = (size_t)(b * 16 + h) * 1024;

  for (int i = tid; i < TLN; i += 256) Tl[i] = Tt[(q0 - k0seg - (KSEG - 1) + 1023) + i];

  s8v aq[2];
  for (int s_ = 0; s_ < 2; s_++)
    aq[s_] = *(const s8v*)&Qc[(size_t)(b * 1024 + qbase + lr) * 1024 + h * 64 + s_ * 32 + lg * 8];

  f32x4 oacc[4];
  for (int n = 0; n < 4; n++) oacc[n] = (f32x4){0.f, 0.f, 0.f, 0.f};
  float dsum[4] = {0.f, 0.f, 0.f, 0.f};
  __syncthreads();

  auto stage = [&](int t, int buf) {
#pragma unroll
    for (int i = 0; i < 2; i++) {
      int n = i * 256 + tid;
      int row = n >> 3, cswz = n & 7, cb = cswz ^ (row & 7);
      gload_lds16(&Kc[(size_t)(b * 1024 + k0seg + t * 64 + row) * 1024 + h * 64 + cb * 8],
                  &Kl[buf][(i * 256 + wid * 64) * 8]);
      gload_lds16(&Vt[((size_t)(b * 16 + h) * 64 + row) * 1024 + k0seg + t * 64 + cb * 8],
                  &Vl[buf][(i * 256 + wid * 64) * 8]);
    }
  };
  auto gather = [&](int t, unsigned short* cg, unsigned short* pg) {
#pragma unroll
    for (int n = 0; n < 4; n++) {
      int k = k0seg + t * 64 + n * 16 + lr;
      size_t prow = (bh1024 + k) * 512;
      int jb = wid * 16 - t * 64 - lr + (KSEG - 1) - n * 16 + lg * 4;
#pragma unroll
      for (int r = 0; r < 4; r++) {
        int q = qbase + lg * 4 + r;
        int idx = Tl[jb + r];
        cg[n * 4 + r] = (unsigned short)c2p[(bh1024 + q) * 512 + idx];
        pg[n * 4 + r] = (unsigned short)p2c[prow + idx];
      }
    }
  };

  unsigned short c2g[16], p2g[16], c2n[16], p2n[16];
  stage(0, 0);
  gather(0, c2g, p2g);
  __syncthreads();

#pragma unroll
  for (int t = 0; t < NT; ++t) {
    const int cur = t & 1, nxt = cur ^ 1;
    if (t + 1 < NT) { stage(t + 1, nxt); gather(t + 1, c2n, p2n); }

    f32x4 sacc[4];
#pragma unroll
    for (int n = 0; n < 4; n++) sacc[n] = (f32x4){0.f, 0.f, 0.f, 0.f};
#pragma unroll
    for (int s_ = 0; s_ < 2; s_++)
#pragma unroll
      for (int n = 0; n < 4; n++) {
        int row = n * 16 + lr, cb = s_ * 4 + lg, cbs = cb ^ (row & 7);
        s8v bk_ = *(const s8v*)&Kl[cur][row * 64 + cbs * 8];
        sacc[n] = __builtin_amdgcn_mfma_f32_16x16x32_bf16(aq[s_], bk_, sacc[n], 0, 0, 0);
      }
#pragma unroll
    for (int n = 0; n < 4; n++)
#pragma unroll
      for (int r = 0; r < 4; r++) {
        float bias = bf2f(c2g[n * 4 + r]) + bf2f(p2g[n * 4 + r]);
        float p = __expf(sacc[n][r] + bias);
        dsum[r] += p;
        Pl[wid][(lg * 4 + r) * 72 + n * 16 + lr] = (short)f2bf(p);
      }
    asm volatile("s_waitcnt lgkmcnt(0)" ::: "memory");
#pragma unroll
    for (int s_ = 0; s_ < 2; s_++) {
      s8v ap = *(const s8v*)&Pl[wid][lr * 72 + s_ * 32 + lg * 8];
#pragma unroll
      for (int n = 0; n < 4; n++) {
        int row = n * 16 + lr, cb = s_ * 4 + lg, cbs = cb ^ (row & 7);
        s8v bv_ = *(const s8v*)&Vl[cur][row * 64 + cbs * 8];
        oacc[n] = __builtin_amdgcn_mfma_f32_16x16x32_bf16(ap, bv_, oacc[n], 0, 0, 0);
      }
    }
    __syncthreads();
    if (t + 1 < NT) {
#pragma unroll
      for (int i = 0; i < 16; i++) { c2g[i] = c2n[i]; p2g[i] = p2n[i]; }
    }
  }

  for (int m = 1; m < 16; m <<= 1)
    for (int r = 0; r < 4; r++) dsum[r] += __shfl_xor(dsum[r], m, 64);

  if (NSPLIT == 1) {
    for (int n = 0; n < 4; n++)
      for (int r = 0; r < 4; r++) {
        int q = qbase + lg * 4 + r;
        int d = n * 16 + lr;
        out[(size_t)(b * 1024 + q) * 1024 + h * 64 + d] = oacc[n][r] / dsum[r];
      }
  } else {
    size_t po = ((size_t)(z * 16 + h)) * 65536;
    for (int n = 0; n < 4; n++)
      for (int r = 0; r < 4; r++) {
        int q = qbase + lg * 4 + r;
        Opart[po + (size_t)q * 64 + n * 16 + lr] = oacc[n][r];
      }
    if (lr == 0)
      for (int r = 0; r < 4; r++)
        dpart[(z * 16 + h) * 1024 + qbase + lg * 4 + r] = dsum[r];
  }
}

// ---------------------------------------------------------------------------
// combine: out = sum_ks Opart / sum_ks dpart
// ---------------------------------------------------------------------------
template <int NSPLIT>
__global__ __launch_bounds__(256) void combine_kernel(
    const float* __restrict__ Opart, const float* __restrict__ dpart,
    float* __restrict__ out) {
  int idx = blockIdx.x * 256 + threadIdx.x;
  int pos = idx * 4;                 // flat out index, 4 floats per thread
  int b = pos >> 20;
  int q = (pos >> 10) & 1023;
  int hd = pos & 1023;
  int h = hd >> 6, d = hd & 63;
  f4v s = (f4v){0.f, 0.f, 0.f, 0.f};
  float dn = 0.f;
  for (int ks = 0; ks < NSPLIT; ks++) {
    int zh = (b * NSPLIT + ks) * 16 + h;
    s += *(const f4v*)&Opart[(size_t)zh * 65536 + q * 64 + d];
    dn += dpart[zh * 1024 + q];
  }
  f4v r = s / dn;
  *(f4v*)&out[pos] = r;
}

// ---------------------------------------------------------------------------
extern "C" void kernel_launch(void* const* d_in, const int* in_sizes, int n_in,
                              void* d_out, int out_size, void* d_ws, size_t ws_size,
                              hipStream_t stream) {
  (void)in_sizes; (void)n_in; (void)out_size;
  const float* hidden = (const float*)d_in[0];
  const int* mask = (const int*)d_in[1];
  const float* rel = (const float*)d_in[2];
  const float* Wq = (const float*)d_in[3];
  const float* bq = (const float*)d_in[4];
  const float* Wk = (const float*)d_in[5];
  const float* bk = (const float*)d_in[6];
  const float* Wv = (const float*)d_in[7];
  const float* bv = (const float*)d_in[8];
  float* out = (float*)d_out;

  char* w = (char*)d_ws;
  short* Abf = (short*)w; w += 2560 * 1024 * 2;          // 5.25 MB
  short* Wbf = (short*)w; w += 3 * 1024 * 1024 * 2;      // 6.29 MB
  short* Qc  = (short*)w; w += 2560 * 1024 * 2;
  short* Kc  = (short*)w; w += 2560 * 1024 * 2;
  short* Vc  = (short*)w; w += 2560 * 1024 * 2;
  short* Vt  = (short*)w; w += 2 * 16 * 64 * 1024 * 2;   // 4.19 MB
  short* c2p = (short*)w; w += (size_t)2 * 16 * 1024 * 512 * 2;  // 33.5 MB
  short* p2c = (short*)w; w += (size_t)2 * 16 * 1024 * 512 * 2;  // 33.5 MB
  short* Tt  = (short*)w; w += 4096;
  float* mbias = (float*)w; w += 8192;
  // frag path: bias matrix appended; Opart/dpart overlay c2p/p2c (dead after
  // bias_build; attn_frag writes Opart only after bias_build completed).
  short* bias_frag = (short*)w;
  size_t need_frag = (size_t)(w - (char*)d_ws) + (size_t)8192 * 4096 * 2;  // +67.1 MB
  // gather path: Opart/dpart appended (c2p/p2c stay live through attn).
  float* Opart_old = (float*)w;
  size_t need_old = (size_t)(w - (char*)d_ws) + (size_t)8 * 16 * 1024 * 64 * 4 + 8 * 16 * 1024 * 4;

  prep_kernel<<<5648, 256, 0, stream>>>(hidden, rel, Wq, Wk, Wv, mask, Abf, Wbf, mbias, Tt);
  gemm_qkv<<<dim3(8, 20, 3), 256, 0, stream>>>(Abf, Wbf, bq, bk, bv, Qc, Kc, Vc);
  pos_trans<<<dim3(4, 8, 80), 256, 0, stream>>>(Qc, Kc, Vc, mbias, c2p, p2c, Vt);

  if (ws_size >= need_frag) {
    float* Opart = (float*)c2p;     // 16.8 MB needed, 33.5 MB region
    float* dpart = (float*)p2c;     // 256 KB into p2c region
    bias_build<<<dim3(16, 16, 32), 256, 0, stream>>>(c2p, p2c, Tt, bias_frag);
    attn_frag<2><<<dim3(16, 16, 4), 256, 0, stream>>>(Qc, Kc, Vt, bias_frag,
                                                      Opart, dpart, out);
    combine_kernel<2><<<2048, 256, 0, stream>>>(Opart, dpart, out);
  } else if (ws_size >= need_old) {
    float* Opart = Opart_old;
    float* dpart = (float*)((char*)Opart_old + (size_t)8 * 16 * 1024 * 64 * 4);
    attn_gather<4><<<dim3(16, 16, 8), 256, 0, stream>>>(Qc, Kc, Vt, c2p, p2c, Tt,
                                                        Opart, dpart, out);
    combine_kernel<4><<<2048, 256, 0, stream>>>(Opart, dpart, out);
  } else {
    attn_gather<1><<<dim3(16, 16, 2), 256, 0, stream>>>(Qc, Kc, Vt, c2p, p2c, Tt,
                                                        (float*)Opart_old, (float*)Opart_old, out);
  }
}

// Round 14
// 136.525 us; speedup vs baseline: 1.6337x; 1.0004x over previous
//
#include <hip/hip_runtime.h>

// ---------------------------------------------------------------------------
// DeBERTa-v2 disentangled self-attention, MI355X (gfx950)
// B=2, L=1024, D=1024, H=16, HEAD=64, ATT_SPAN=256 (pos dim 512), scale=sqrt(192)
// ---------------------------------------------------------------------------

typedef short s8v __attribute__((ext_vector_type(8)));
typedef short s4v __attribute__((ext_vector_type(4)));
typedef float f32x4 __attribute__((ext_vector_type(4)));
typedef float f4v __attribute__((ext_vector_type(4)));

#define QK_SCALE 0.26864243f   // 192^(-1/4); folded so all score terms get /sqrt(192)

__device__ __forceinline__ unsigned short f2bf(float f) {
  unsigned u = __builtin_bit_cast(unsigned, f);
  u += 0x7fffu + ((u >> 16) & 1u);          // RNE
  return (unsigned short)(u >> 16);
}
__device__ __forceinline__ float bf2f(unsigned short h) {
  unsigned u = ((unsigned)h) << 16;
  return __builtin_bit_cast(float, u);
}

__device__ __forceinline__ void gload_lds16(const void* g, void* l) {
  __builtin_amdgcn_global_load_lds(
      (const __attribute__((address_space(1))) void*)g,
      (__attribute__((address_space(3))) void*)l, 16, 0, 0);
}

// ---------------------------------------------------------------------------
// prep: f32->bf16 conversions, bucket table, mask bias
// ---------------------------------------------------------------------------
__global__ __launch_bounds__(256) void prep_kernel(
    const float* __restrict__ hidden, const float* __restrict__ rel,
    const float* __restrict__ Wq, const float* __restrict__ Wk,
    const float* __restrict__ Wv, const int* __restrict__ mask,
    short* __restrict__ Abf, short* __restrict__ Wbf,
    float* __restrict__ mbias, short* __restrict__ Tt) {
  int idx = blockIdx.x * 256 + threadIdx.x;
  const int NCONV = 1441792;  // (2560*1024 + 3*1024*1024)/4 float4s
  if (idx < NCONV) {
    const float* src; short* dst; int off;
    if (idx < 524288) { src = hidden; dst = Abf; off = idx; }
    else if (idx < 655360) { src = rel; dst = Abf + 2048 * 1024; off = idx - 524288; }
    else {
      int j = idx - 655360;
      int w = j / 262144; off = j - w * 262144;
      src = (w == 0) ? Wq : (w == 1) ? Wk : Wv;
      dst = Wbf + w * 1048576;
    }
    f4v v = ((const f4v*)src)[off];
    s4v o;
    o[0] = (short)f2bf(v[0]); o[1] = (short)f2bf(v[1]);
    o[2] = (short)f2bf(v[2]); o[3] = (short)f2bf(v[3]);
    ((s4v*)dst)[off] = o;
  } else {
    int j = idx - NCONV;
    if (j < 2047) {
      int r = j - 1023;
      float fr = (float)r;
      float sign = (r > 0) ? 1.f : ((r < 0) ? -1.f : 0.f);
      float abs_pos = (r < 128 && r > -128) ? 127.f : fabsf(fr);
      const float logc = 1.3843393245589053f;  // f32(log(511/128))
      float log_pos = ceilf(logf(abs_pos * (1.f / 128.f)) / logc * 127.f) + 128.f;
      float bucket = (abs_pos <= 128.f) ? fr : log_pos * sign;
      int bi = (int)bucket + 256;
      bi = bi < 0 ? 0 : (bi > 511 ? 511 : bi);
      Tt[j] = (short)bi;
    } else if (j < 4095) {
      int m = j - 2047;
      mbias[m] = (mask[m] > 0) ? 0.f : -1e9f;
    }
  }
}

// ---------------------------------------------------------------------------
// gemm_qkv: C[m,n] = (sum_k A[m,k]*W[n,k] + bias[n]) * scale, bf16 out
//   128x128 tile, XOR-SWIZZLED LDS (R9: conflicts 8.26M -> fixed).
//   z==2 (V): position rows (>=2048) never consumed -> early exit.
// ---------------------------------------------------------------------------
__global__ __launch_bounds__(256) void gemm_qkv(
    const short* __restrict__ Abf, const short* __restrict__ Wbf,
    const float* __restrict__ bq, const float* __restrict__ bk,
    const float* __restrict__ bv,
    short* __restrict__ Qc, short* __restrict__ Kc, short* __restrict__ Vc) {
  __shared__ short As[128 * 64];
  __shared__ short Bs[128 * 64];
  int tid = threadIdx.x;
  int wid = tid >> 6, lane = tid & 63;
  int lr = lane & 15, lg = lane >> 4;
  int wr = wid >> 1, wc = wid & 1;
  int z = blockIdx.z;
  int brow = blockIdx.y * 128;
  if (z == 2 && brow >= 2048) return;   // V pos-rows unused
  const short* W = Wbf + z * 1048576;
  const float* bias = (z == 0) ? bq : (z == 1) ? bk : bv;
  short* C = (z == 0) ? Qc : (z == 1) ? Kc : Vc;
  float scale = (z == 2) ? 1.f : QK_SCALE;
  int bcol = blockIdx.x * 128;

  f32x4 acc[4][4];
  for (int i = 0; i < 4; i++)
    for (int j = 0; j < 4; j++) acc[i][j] = (f32x4){0.f, 0.f, 0.f, 0.f};

  for (int k0 = 0; k0 < 1024; k0 += 64) {
    for (int i = 0; i < 4; i++) {
      int n = i * 256 + wid * 64 + lane;
      int row = n >> 3, cswz = n & 7, cb = cswz ^ (row & 7);
      const short* gA = Abf + (size_t)(brow + row) * 1024 + k0 + cb * 8;
      gload_lds16(gA, &As[(i * 256 + wid * 64) * 8]);
      const short* gB = W + (size_t)(bcol + row) * 1024 + k0 + cb * 8;
      gload_lds16(gB, &Bs[(i * 256 + wid * 64) * 8]);
    }
    __syncthreads();
    for (int ks = 0; ks < 2; ks++) {
      s8v af[4], bfv[4];
      for (int mi = 0; mi < 4; mi++) {
        int row = wr * 64 + mi * 16 + lr, cb = ks * 4 + lg;
        af[mi] = *(const s8v*)&As[row * 64 + (cb ^ (row & 7)) * 8];
      }
      for (int ni = 0; ni < 4; ni++) {
        int row = wc * 64 + ni * 16 + lr, cb = ks * 4 + lg;
        bfv[ni] = *(const s8v*)&Bs[row * 64 + (cb ^ (row & 7)) * 8];
      }
      for (int mi = 0; mi < 4; mi++)
        for (int ni = 0; ni < 4; ni++)
          acc[mi][ni] = __builtin_amdgcn_mfma_f32_16x16x32_bf16(
              af[mi], bfv[ni], acc[mi][ni], 0, 0, 0);
    }
    __syncthreads();
  }
  for (int mi = 0; mi < 4; mi++)
    for (int ni = 0; ni < 4; ni++) {
      int col = bcol + wc * 64 + ni * 16 + lr;
      float bb = bias[col];
      for (int r = 0; r < 4; r++) {
        int row = brow + wr * 64 + mi * 16 + lg * 4 + r;
        float v = (acc[mi][ni][r] + bb) * scale;
        C[(size_t)row * 1024 + col] = (short)f2bf(v);
      }
    }
}

// ---------------------------------------------------------------------------
// pos_trans: MERGED pos_gemm (z<64) + transpose_v (z>=64).
//   pos part XOR-SWIZZLED (same fix as gemm_qkv R9; linear [row][64] LDS
//   fragment reads are a 16-way ds_read_b128 bank conflict).
//   pos part:  which=0: c2p[bh][q][p] = Q[q].posK[p]
//              which=1: p2c[bh][k][p] = K[k].posQ[p] + mbias[b,k]
//   trans part: Vt[b,h,d,l] = Vc[b*1024+l, h*64+d]
// ---------------------------------------------------------------------------
__global__ __launch_bounds__(256) void pos_trans(
    const short* __restrict__ Qc, const short* __restrict__ Kc,
    const short* __restrict__ Vc, const float* __restrict__ mbias,
    short* __restrict__ c2p, short* __restrict__ p2c,
    short* __restrict__ Vt) {
  __shared__ short sh[2 * 128 * 64];
  int tid = threadIdx.x;
  if (blockIdx.z < 64) {
    short* As = sh;
    short* Bs = sh + 128 * 64;
    int wid = tid >> 6, lane = tid & 63;
    int lr = lane & 15, lg = lane >> 4;
    int wr = wid >> 1, wc = wid & 1;
    int zz = blockIdx.z;       // 0..63
    int which = zz >> 5;
    int bh = zz & 31;
    int b = bh >> 4, h = bh & 15;
    const short* Arows = (which == 0) ? Qc : Kc;   // content source
    const short* Brows = (which == 0) ? Kc : Qc;   // pos-projection source
    short* Out = (which == 0) ? c2p : p2c;
    int mrow = blockIdx.y * 128;   // content base (1024/128 = 8)
    int ncol = blockIdx.x * 128;   // bucket base  (512/128 = 4)

    for (int i = 0; i < 4; i++) {
      int n = i * 256 + wid * 64 + lane;
      int row = n >> 3, cswz = n & 7, cb = cswz ^ (row & 7);
      const short* gA = Arows + (size_t)(b * 1024 + mrow + row) * 1024 + h * 64 + cb * 8;
      gload_lds16(gA, &As[(i * 256 + wid * 64) * 8]);
      const short* gB = Brows + (size_t)(2048 + ncol + row) * 1024 + h * 64 + cb * 8;
      gload_lds16(gB, &Bs[(i * 256 + wid * 64) * 8]);
    }
    __syncthreads();

    f32x4 acc[4][4];
    for (int i = 0; i < 4; i++)
      for (int j = 0; j < 4; j++) acc[i][j] = (f32x4){0.f, 0.f, 0.f, 0.f};
    for (int ks = 0; ks < 2; ks++) {
      s8v af[4], bfv[4];
      for (int mi = 0; mi < 4; mi++) {   // A-operand = content rows
        int row = wr * 64 + mi * 16 + lr, cb = ks * 4 + lg;
        af[mi] = *(const s8v*)&As[row * 64 + (cb ^ (row & 7)) * 8];
      }
      for (int ni = 0; ni < 4; ni++) {   // B-operand = bucket rows
        int row = wc * 64 + ni * 16 + lr, cb = ks * 4 + lg;
        bfv[ni] = *(const s8v*)&Bs[row * 64 + (cb ^ (row & 7)) * 8];
      }
      for (int mi = 0; mi < 4; mi++)
        for (int ni = 0; ni < 4; ni++)
          acc[mi][ni] = __builtin_amdgcn_mfma_f32_16x16x32_bf16(
              af[mi], bfv[ni], acc[mi][ni], 0, 0, 0);
    }
    size_t base = (size_t)(b * 16 + h) * 1024;
    for (int mi = 0; mi < 4; mi++)
      for (int ni = 0; ni < 4; ni++)
        for (int r = 0; r < 4; r++) {
          int m = mrow + wr * 64 + mi * 16 + lg * 4 + r;   // content row
          int nn = ncol + wc * 64 + ni * 16 + lr;          // bucket col
          float v = acc[mi][ni][r];
          if (which == 1) v += mbias[b * 1024 + m];
          Out[(base + m) * 512 + nn] = (short)f2bf(v);
        }
  } else {
    short* TL = sh;   // 64*72 elems
    int idx = ((blockIdx.z - 64) * 8 + blockIdx.y) * 4 + blockIdx.x;  // 0..511
    int b = idx >> 8, h = (idx >> 4) & 15, lt = idx & 15;
    for (int i = 0; i < 2; i++) {
      int n = i * 256 + tid;
      int l = n >> 3, c = n & 7;
      s8v v = *(const s8v*)&Vc[(size_t)(b * 1024 + lt * 64 + l) * 1024 + h * 64 + c * 8];
      *(s8v*)&TL[l * 72 + c * 8] = v;
    }
    __syncthreads();
    for (int i = 0; i < 2; i++) {
      int m = i * 256 + tid;
      int d = m >> 3, c = m & 7;
      s8v o;
      for (int jj = 0; jj < 8; jj++) o[jj] = TL[(c * 8 + jj) * 72 + d];
      *(s8v*)&Vt[((size_t)(b * 16 + h) * 64 + d) * 1024 + lt * 64 + c * 8] = o;
    }
  }
}

// ---------------------------------------------------------------------------
// bias_build: block = one 64x64 (q,k) tile of one (b,h). Materializes
//   bias[q,k] = c2p[q][T[q-k]] + p2c[k][T[q-k]]  (mask already in p2c)
//   in MFMA FRAGMENT ORDER so attn reads it with 2 coalesced dwordx4/lane.
// ---------------------------------------------------------------------------
__global__ __launch_bounds__(256) void bias_build(
    const short* __restrict__ c2p, const short* __restrict__ p2c,
    const short* __restrict__ Tt, short* __restrict__ bias) {
  __shared__ short Wc[64 * 66];
  __shared__ short Wp[64 * 66];
  __shared__ short Tl[128];
  int tid = threadIdx.x;
  int wid = tid >> 6, lane = tid & 63;
  int lr = lane & 15, lg = lane >> 4;
  int qt = blockIdx.x, kt = blockIdx.y, bh = blockIdx.z;
  int q0 = qt * 64, k0 = kt * 64;
  int relbase = q0 - k0;
  size_t bh1024 = (size_t)bh * 1024;

  // Tl[i] = T[relbase - 63 + i], i in [0,126]; Tt index = rel + 1023
  if (tid < 127) Tl[tid] = Tt[relbase + 960 + tid];
  __syncthreads();

#pragma unroll
  for (int ii = 0; ii < 16; ii++) {
    int row = wid * 16 + ii;                 // uniform within wave
    int w0 = Tl[row];                        // window base for c2p row
    int col = w0 + lane; col = col > 511 ? 511 : col;
    Wc[row * 66 + lane] = c2p[(bh1024 + q0 + row) * 512 + col];
    int w0p_ = Tl[63 - row];                 // window base for p2c row
    int colp = w0p_ + lane; colp = colp > 511 ? 511 : colp;
    Wp[row * 66 + lane] = p2c[(bh1024 + k0 + row) * 512 + colp];
  }
  __syncthreads();

  int w0c[4], w0p[4];
#pragma unroll
  for (int r = 0; r < 4; r++) w0c[r] = Tl[wid * 16 + lg * 4 + r];
#pragma unroll
  for (int n = 0; n < 4; n++) w0p[n] = Tl[63 - (n * 16 + lr)];

  s8v o0, o1;
#pragma unroll
  for (int n = 0; n < 4; n++)
#pragma unroll
    for (int r = 0; r < 4; r++) {
      int qq = wid * 16 + lg * 4 + r;
      int kk = n * 16 + lr;
      int p = Tl[qq - kk + 63];
      float v = bf2f((unsigned short)Wc[qq * 66 + p - w0c[r]]) +
                bf2f((unsigned short)Wp[kk * 66 + p - w0p[n]]);
      short s = (short)f2bf(v);
      if (n < 2) o0[(n & 1) * 4 + r] = s; else o1[(n & 1) * 4 + r] = s;
    }
  size_t tile = ((size_t)bh * 16 + qt) * 16 + kt;
  size_t base = (tile * 4 + wid) * 1024 + lane * 8;
  *(s8v*)&bias[base] = o0;
  *(s8v*)&bias[base + 512] = o1;
}

// ---------------------------------------------------------------------------
// attn_frag: double-buffered skeleton, bias read as 2 coalesced
//   fragment-ordered loads per tile (prefetched one tile ahead).
//   NSPLIT=2; separate combine launch (R12: fused combine via __threadfence
//   thrashes per-XCD L2 -> 4x slowdown).
//   Pl stride 72 -> 64 + chunk-XOR swizzle: LDS 41984 -> 40960 B, so
//   4 blocks/CU fit (was 3) -- attn is latency/occupancy-bound (R10).
// ---------------------------------------------------------------------------
template <int NSPLIT>
__global__ __launch_bounds__(256) void attn_frag(
    const short* __restrict__ Qc, const short* __restrict__ Kc,
    const short* __restrict__ Vt, const short* __restrict__ bias,
    float* __restrict__ Opart, float* __restrict__ dpart,
    float* __restrict__ out) {
  const int KSEG = 1024 / NSPLIT;
  const int NT = KSEG / 64;
  __shared__ short Kl[2][64 * 64];
  __shared__ short Vl[2][64 * 64];
  __shared__ short Pl[4][16 * 64];
  int tid = threadIdx.x;
  int wid = tid >> 6, lane = tid & 63;
  int lr = lane & 15, lg = lane >> 4;
  int qt = blockIdx.x, h = blockIdx.y, z = blockIdx.z;
  int b = (NSPLIT == 1) ? z : (z / NSPLIT);
  int ks = (NSPLIT == 1) ? 0 : (z % NSPLIT);
  int k0seg = ks * KSEG;
  int q0 = qt * 64, qbase = q0 + wid * 16;

  // Q fragments (held in registers for the whole kernel)
  s8v aq[2];
  for (int s_ = 0; s_ < 2; s_++)
    aq[s_] = *(const s8v*)&Qc[(size_t)(b * 1024 + qbase + lr) * 1024 + h * 64 + s_ * 32 + lg * 8];

  f32x4 oacc[4];
  for (int n = 0; n < 4; n++) oacc[n] = (f32x4){0.f, 0.f, 0.f, 0.f};
  float dsum[4] = {0.f, 0.f, 0.f, 0.f};

  auto stage = [&](int t, int buf) {
#pragma unroll
    for (int i = 0; i < 2; i++) {
      int n = i * 256 + tid;
      int row = n >> 3, cswz = n & 7, cb = cswz ^ (row & 7);
      gload_lds16(&Kc[(size_t)(b * 1024 + k0seg + t * 64 + row) * 1024 + h * 64 + cb * 8],
                  &Kl[buf][(i * 256 + wid * 64) * 8]);
      gload_lds16(&Vt[((size_t)(b * 16 + h) * 64 + row) * 1024 + k0seg + t * 64 + cb * 8],
                  &Vl[buf][(i * 256 + wid * 64) * 8]);
    }
  };
  auto fload = [&](int t, s8v& f0, s8v& f1) {
    size_t tile = (((size_t)(b * 16 + h) * 16 + qt) * 16 + (k0seg >> 6) + t);
    size_t base = (tile * 4 + wid) * 1024 + lane * 8;
    f0 = *(const s8v*)&bias[base];
    f1 = *(const s8v*)&bias[base + 512];
  };

  s8v fb0, fb1, fn0, fn1;
  stage(0, 0);
  fload(0, fb0, fb1);
  __syncthreads();   // drains stage(0)+fload(0)

#pragma unroll
  for (int t = 0; t < NT; ++t) {
    const int cur = t & 1, nxt = cur ^ 1;

    // A) issue next tile's async loads FIRST — overlap this tile's compute
    if (t + 1 < NT) {
      stage(t + 1, nxt);
      fload(t + 1, fn0, fn1);
    }

    // B) S = Q . K^T  (wave: 16 q x 64 k) from Kl[cur]
    f32x4 sacc[4];
#pragma unroll
    for (int n = 0; n < 4; n++) sacc[n] = (f32x4){0.f, 0.f, 0.f, 0.f};
#pragma unroll
    for (int s_ = 0; s_ < 2; s_++)
#pragma unroll
      for (int n = 0; n < 4; n++) {
        int row = n * 16 + lr, cb = s_ * 4 + lg, cbs = cb ^ (row & 7);
        s8v bk_ = *(const s8v*)&Kl[cur][row * 64 + cbs * 8];
        sacc[n] = __builtin_amdgcn_mfma_f32_16x16x32_bf16(aq[s_], bk_, sacc[n], 0, 0, 0);
      }

    // C) add fragment bias (registers), exp, write P (chunk-XOR swizzled)
#pragma unroll
    for (int n = 0; n < 4; n++)
#pragma unroll
      for (int r = 0; r < 4; r++) {
        unsigned short bv_ = (unsigned short)((n < 2 ? fb0 : fb1)[(n & 1) * 4 + r]);
        float p = __expf(sacc[n][r] + bf2f(bv_));
        dsum[r] += p;
        int prow = lg * 4 + r, pc = n * 16 + lr;
        int pcb = (pc >> 3) ^ (prow & 7);
        Pl[wid][prow * 64 + pcb * 8 + (pc & 7)] = (short)f2bf(p);
      }
    asm volatile("s_waitcnt lgkmcnt(0)" ::: "memory");

    // D) O += P . Vt^T  (wave: 16 q x 64 d) from Vl[cur]
#pragma unroll
    for (int s_ = 0; s_ < 2; s_++) {
      int pcb = (s_ * 4 + lg) ^ (lr & 7);
      s8v ap = *(const s8v*)&Pl[wid][lr * 64 + pcb * 8];
#pragma unroll
      for (int n = 0; n < 4; n++) {
        int row = n * 16 + lr, cb = s_ * 4 + lg, cbs = cb ^ (row & 7);
        s8v bv_ = *(const s8v*)&Vl[cur][row * 64 + cbs * 8];
        oacc[n] = __builtin_amdgcn_mfma_f32_16x16x32_bf16(ap, bv_, oacc[n], 0, 0, 0);
      }
    }

    // E) single barrier per tile
    __syncthreads();

    // F) rotate prefetched fragments
    if (t + 1 < NT) { fb0 = fn0; fb1 = fn1; }
  }

  for (int m = 1; m < 16; m <<= 1)
    for (int r = 0; r < 4; r++) dsum[r] += __shfl_xor(dsum[r], m, 64);

  if (NSPLIT == 1) {
    for (int n = 0; n < 4; n++)
      for (int r = 0; r < 4; r++) {
        int q = qbase + lg * 4 + r;
        int d = n * 16 + lr;
        out[(size_t)(b * 1024 + q) * 1024 + h * 64 + d] = oacc[n][r] / dsum[r];
      }
  } else {
    size_t po = ((size_t)(z * 16 + h)) * 65536;
    for (int n = 0; n < 4; n++)
      for (int r = 0; r < 4; r++) {
        int q = qbase + lg * 4 + r;
        Opart[po + (size_t)q * 64 + n * 16 + lr] = oacc[n][r];
      }
    if (lr == 0)
      for (int r = 0; r < 4; r++)
        dpart[(z * 16 + h) * 1024 + qbase + lg * 4 + r] = dsum[r];
  }
}

// ---------------------------------------------------------------------------
// attn_gather: fallback (used only if workspace too small for bias_frag)
// ---------------------------------------------------------------------------
template <int NSPLIT>
__global__ __launch_bounds__(256) void attn_gather(
    const short* __restrict__ Qc, const short* __restrict__ Kc,
    const short* __restrict__ Vt, const short* __restrict__ c2p,
    const short* __restrict__ p2c, const short* __restrict__ Tt,
    float* __restrict__ Opart, float* __restrict__ dpart,
    float* __restrict__ out) {
  const int KSEG = 1024 / NSPLIT;
  const int NT = KSEG / 64;
  const int TLN = 64 + KSEG - 1;
  __shared__ short Kl[2][64 * 64];
  __shared__ short Vl[2][64 * 64];
  __shared__ short Pl[4][16 * 72];
  __shared__ short Tl[TLN + 1];
  int tid = threadIdx.x;
  int wid = tid >> 6, lane = tid & 63;
  int lr = lane & 15, lg = lane >> 4;
  int qt = blockIdx.x, h = blockIdx.y, z = blockIdx.z;
  int b = (NSPLIT == 1) ? z : (z / NSPLIT);
  int ks = (NSPLIT == 1) ? 0 : (z % NSPLIT);
  int k0seg = ks * KSEG;
  int q0 = qt * 64, qbase = q0 + wid * 16;
  size_t bh1024 = (size_t)(b * 16 + h) * 1024;

  for (int i = tid; i < TLN; i += 256) Tl[i] = Tt[(q0 - k0seg - (KSEG - 1) + 1023) + i];

  s8v aq[2];
  for (int s_ = 0; s_ < 2; s_++)
    aq[s_] = *(const s8v*)&Qc[(size_t)(b * 1024 + qbase + lr) * 1024 + h * 64 + s_ * 32 + lg * 8];

  f32x4 oacc[4];
  for (int n = 0; n < 4; n++) oacc[n] = (f32x4){0.f, 0.f, 0.f, 0.f};
  float dsum[4] = {0.f, 0.f, 0.f, 0.f};
  __syncthreads();

  auto stage = [&](int t, int buf) {
#pragma unroll
    for (int i = 0; i < 2; i++) {
      int n = i * 256 + tid;
      int row = n >> 3, cswz = n & 7, cb = cswz ^ (row & 7);
      gload_lds16(&Kc[(size_t)(b * 1024 + k0seg + t * 64 + row) * 1024 + h * 64 + cb * 8],
                  &Kl[buf][(i * 256 + wid * 64) * 8]);
      gload_lds16(&Vt[((size_t)(b * 16 + h) * 64 + row) * 1024 + k0seg + t * 64 + cb * 8],
                  &Vl[buf][(i * 256 + wid * 64) * 8]);
    }
  };
  auto gather = [&](int t, unsigned short* cg, unsigned short* pg) {
#pragma unroll
    for (int n = 0; n < 4; n++) {
      int k = k0seg + t * 64 + n * 16 + lr;
      size_t prow = (bh1024 + k) * 512;
      int jb = wid * 16 - t * 64 - lr + (KSEG - 1) - n * 16 + lg * 4;
#pragma unroll
      for (int r = 0; r < 4; r++) {
        int q = qbase + lg * 4 + r;
        int idx = Tl[jb + r];
        cg[n * 4 + r] = (unsigned short)c2p[(bh1024 + q) * 512 + idx];
        pg[n * 4 + r] = (unsigned short)p2c[prow + idx];
      }
    }
  };

  unsigned short c2g[16], p2g[16], c2n[16], p2n[16];
  stage(0, 0);
  gather(0, c2g, p2g);
  __syncthreads();

#pragma unroll
  for (int t = 0; t < NT; ++t) {
    const int cur = t & 1, nxt = cur ^ 1;
    if (t + 1 < NT) { stage(t + 1, nxt); gather(t + 1, c2n, p2n); }

    f32x4 sacc[4];
#pragma unroll
    for (int n = 0; n < 4; n++) sacc[n] = (f32x4){0.f, 0.f, 0.f, 0.f};
#pragma unroll
    for (int s_ = 0; s_ < 2; s_++)
#pragma unroll
      for (int n = 0; n < 4; n++) {
        int row = n * 16 + lr, cb = s_ * 4 + lg, cbs = cb ^ (row & 7);
        s8v bk_ = *(const s8v*)&Kl[cur][row * 64 + cbs * 8];
        sacc[n] = __builtin_amdgcn_mfma_f32_16x16x32_bf16(aq[s_], bk_, sacc[n], 0, 0, 0);
      }
#pragma unroll
    for (int n = 0; n < 4; n++)
#pragma unroll
      for (int r = 0; r < 4; r++) {
        float bias = bf2f(c2g[n * 4 + r]) + bf2f(p2g[n * 4 + r]);
        float p = __expf(sacc[n][r] + bias);
        dsum[r] += p;
        Pl[wid][(lg * 4 + r) * 72 + n * 16 + lr] = (short)f2bf(p);
      }
    asm volatile("s_waitcnt lgkmcnt(0)" ::: "memory");
#pragma unroll
    for (int s_ = 0; s_ < 2; s_++) {
      s8v ap = *(const s8v*)&Pl[wid][lr * 72 + s_ * 32 + lg * 8];
#pragma unroll
      for (int n = 0; n < 4; n++) {
        int row = n * 16 + lr, cb = s_ * 4 + lg, cbs = cb ^ (row & 7);
        s8v bv_ = *(const s8v*)&Vl[cur][row * 64 + cbs * 8];
        oacc[n] = __builtin_amdgcn_mfma_f32_16x16x32_bf16(ap, bv_, oacc[n], 0, 0, 0);
      }
    }
    __syncthreads();
    if (t + 1 < NT) {
#pragma unroll
      for (int i = 0; i < 16; i++) { c2g[i] = c2n[i]; p2g[i] = p2n[i]; }
    }
  }

  for (int m = 1; m < 16; m <<= 1)
    for (int r = 0; r < 4; r++) dsum[r] += __shfl_xor(dsum[r], m, 64);

  if (NSPLIT == 1) {
    for (int n = 0; n < 4; n++)
      for (int r = 0; r < 4; r++) {
        int q = qbase + lg * 4 + r;
        int d = n * 16 + lr;
        out[(size_t)(b * 1024 + q) * 1024 + h * 64 + d] = oacc[n][r] / dsum[r];
      }
  } else {
    size_t po = ((size_t)(z * 16 + h)) * 65536;
    for (int n = 0; n < 4; n++)
      for (int r = 0; r < 4; r++) {
        int q = qbase + lg * 4 + r;
        Opart[po + (size_t)q * 64 + n * 16 + lr] = oacc[n][r];
      }
    if (lr == 0)
      for (int r = 0; r < 4; r++)
        dpart[(z * 16 + h) * 1024 + qbase + lg * 4 + r] = dsum[r];
  }
}

// ---------------------------------------------------------------------------
// combine: out = sum_ks Opart / sum_ks dpart
// ---------------------------------------------------------------------------
template <int NSPLIT>
__global__ __launch_bounds__(256) void combine_kernel(
    const float* __restrict__ Opart, const float* __restrict__ dpart,
    float* __restrict__ out) {
  int idx = blockIdx.x * 256 + threadIdx.x;
  int pos = idx * 4;                 // flat out index, 4 floats per thread
  int b = pos >> 20;
  int q = (pos >> 10) & 1023;
  int hd = pos & 1023;
  int h = hd >> 6, d = hd & 63;
  f4v s = (f4v){0.f, 0.f, 0.f, 0.f};
  float dn = 0.f;
  for (int ks = 0; ks < NSPLIT; ks++) {
    int zh = (b * NSPLIT + ks) * 16 + h;
    s += *(const f4v*)&Opart[(size_t)zh * 65536 + q * 64 + d];
    dn += dpart[zh * 1024 + q];
  }
  f4v r = s / dn;
  *(f4v*)&out[pos] = r;
}

// ---------------------------------------------------------------------------
extern "C" void kernel_launch(void* const* d_in, const int* in_sizes, int n_in,
                              void* d_out, int out_size, void* d_ws, size_t ws_size,
                              hipStream_t stream) {
  (void)in_sizes; (void)n_in; (void)out_size;
  const float* hidden = (const float*)d_in[0];
  const int* mask = (const int*)d_in[1];
  const float* rel = (const float*)d_in[2];
  const float* Wq = (const float*)d_in[3];
  const float* bq = (const float*)d_in[4];
  const float* Wk = (const float*)d_in[5];
  const float* bk = (const float*)d_in[6];
  const float* Wv = (const float*)d_in[7];
  const float* bv = (const float*)d_in[8];
  float* out = (float*)d_out;

  char* w = (char*)d_ws;
  short* Abf = (short*)w; w += 2560 * 1024 * 2;          // 5.25 MB
  short* Wbf = (short*)w; w += 3 * 1024 * 1024 * 2;      // 6.29 MB
  short* Qc  = (short*)w; w += 2560 * 1024 * 2;
  short* Kc  = (short*)w; w += 2560 * 1024 * 2;
  short* Vc  = (short*)w; w += 2560 * 1024 * 2;
  short* Vt  = (short*)w; w += 2 * 16 * 64 * 1024 * 2;   // 4.19 MB
  short* c2p = (short*)w; w += (size_t)2 * 16 * 1024 * 512 * 2;  // 33.5 MB
  short* p2c = (short*)w; w += (size_t)2 * 16 * 1024 * 512 * 2;  // 33.5 MB
  short* Tt  = (short*)w; w += 4096;
  float* mbias = (float*)w; w += 8192;
  // frag path: bias matrix appended; Opart/dpart overlay c2p/p2c (dead after
  // bias_build; attn_frag writes Opart only after bias_build completed).
  short* bias_frag = (short*)w;
  size_t need_frag = (size_t)(w - (char*)d_ws) + (size_t)8192 * 4096 * 2;  // +67.1 MB
  // gather path: Opart/dpart appended (c2p/p2c stay live through attn).
  float* Opart_old = (float*)w;
  size_t need_old = (size_t)(w - (char*)d_ws) + (size_t)8 * 16 * 1024 * 64 * 4 + 8 * 16 * 1024 * 4;

  prep_kernel<<<5648, 256, 0, stream>>>(hidden, rel, Wq, Wk, Wv, mask, Abf, Wbf, mbias, Tt);
  gemm_qkv<<<dim3(8, 20, 3), 256, 0, stream>>>(Abf, Wbf, bq, bk, bv, Qc, Kc, Vc);
  pos_trans<<<dim3(4, 8, 80), 256, 0, stream>>>(Qc, Kc, Vc, mbias, c2p, p2c, Vt);

  if (ws_size >= need_frag) {
    float* Opart = (float*)c2p;     // 16.8 MB needed, 33.5 MB region
    float* dpart = (float*)p2c;     // 256 KB into p2c region
    bias_build<<<dim3(16, 16, 32), 256, 0, stream>>>(c2p, p2c, Tt, bias_frag);
    attn_frag<2><<<dim3(16, 16, 4), 256, 0, stream>>>(Qc, Kc, Vt, bias_frag,
                                                      Opart, dpart, out);
    combine_kernel<2><<<2048, 256, 0, stream>>>(Opart, dpart, out);
  } else if (ws_size >= need_old) {
    float* Opart = Opart_old;
    float* dpart = (float*)((char*)Opart_old + (size_t)8 * 16 * 1024 * 64 * 4);
    attn_gather<4><<<dim3(16, 16, 8), 256, 0, stream>>>(Qc, Kc, Vt, c2p, p2c, Tt,
                                                        Opart, dpart, out);
    combine_kernel<4><<<2048, 256, 0, stream>>>(Opart, dpart, out);
  } else {
    attn_gather<1><<<dim3(16, 16, 2), 256, 0, stream>>>(Qc, Kc, Vt, c2p, p2c, Tt,
                                                        (float*)Opart_old, (float*)Opart_old, out);
  }
}

// Round 15
// 135.005 us; speedup vs baseline: 1.6521x; 1.0113x over previous
//
#include <hip/hip_runtime.h>

// ---------------------------------------------------------------------------
// DeBERTa-v2 disentangled self-attention, MI355X (gfx950)
// B=2, L=1024, D=1024, H=16, HEAD=64, ATT_SPAN=256 (pos dim 512), scale=sqrt(192)
// ---------------------------------------------------------------------------

typedef short s8v __attribute__((ext_vector_type(8)));
typedef short s4v __attribute__((ext_vector_type(4)));
typedef float f32x4 __attribute__((ext_vector_type(4)));
typedef float f4v __attribute__((ext_vector_type(4)));

#define QK_SCALE 0.26864243f   // 192^(-1/4); folded so all score terms get /sqrt(192)

__device__ __forceinline__ unsigned short f2bf(float f) {
  unsigned u = __builtin_bit_cast(unsigned, f);
  u += 0x7fffu + ((u >> 16) & 1u);          // RNE
  return (unsigned short)(u >> 16);
}
__device__ __forceinline__ float bf2f(unsigned short h) {
  unsigned u = ((unsigned)h) << 16;
  return __builtin_bit_cast(float, u);
}

__device__ __forceinline__ void gload_lds16(const void* g, void* l) {
  __builtin_amdgcn_global_load_lds(
      (const __attribute__((address_space(1))) void*)g,
      (__attribute__((address_space(3))) void*)l, 16, 0, 0);
}

// ---------------------------------------------------------------------------
// prep: f32->bf16 conversions, bucket table, mask bias
// ---------------------------------------------------------------------------
__global__ __launch_bounds__(256) void prep_kernel(
    const float* __restrict__ hidden, const float* __restrict__ rel,
    const float* __restrict__ Wq, const float* __restrict__ Wk,
    const float* __restrict__ Wv, const int* __restrict__ mask,
    short* __restrict__ Abf, short* __restrict__ Wbf,
    float* __restrict__ mbias, short* __restrict__ Tt) {
  int idx = blockIdx.x * 256 + threadIdx.x;
  const int NCONV = 1441792;  // (2560*1024 + 3*1024*1024)/4 float4s
  if (idx < NCONV) {
    const float* src; short* dst; int off;
    if (idx < 524288) { src = hidden; dst = Abf; off = idx; }
    else if (idx < 655360) { src = rel; dst = Abf + 2048 * 1024; off = idx - 524288; }
    else {
      int j = idx - 655360;
      int w = j / 262144; off = j - w * 262144;
      src = (w == 0) ? Wq : (w == 1) ? Wk : Wv;
      dst = Wbf + w * 1048576;
    }
    f4v v = ((const f4v*)src)[off];
    s4v o;
    o[0] = (short)f2bf(v[0]); o[1] = (short)f2bf(v[1]);
    o[2] = (short)f2bf(v[2]); o[3] = (short)f2bf(v[3]);
    ((s4v*)dst)[off] = o;
  } else {
    int j = idx - NCONV;
    if (j < 2047) {
      int r = j - 1023;
      float fr = (float)r;
      float sign = (r > 0) ? 1.f : ((r < 0) ? -1.f : 0.f);
      float abs_pos = (r < 128 && r > -128) ? 127.f : fabsf(fr);
      const float logc = 1.3843393245589053f;  // f32(log(511/128))
      float log_pos = ceilf(logf(abs_pos * (1.f / 128.f)) / logc * 127.f) + 128.f;
      float bucket = (abs_pos <= 128.f) ? fr : log_pos * sign;
      int bi = (int)bucket + 256;
      bi = bi < 0 ? 0 : (bi > 511 ? 511 : bi);
      Tt[j] = (short)bi;
    } else if (j < 4095) {
      int m = j - 2047;
      mbias[m] = (mask[m] > 0) ? 0.f : -1e9f;
    }
  }
}

// ---------------------------------------------------------------------------
// gemm_qkv: C[m,n] = (sum_k A[m,k]*W[n,k] + bias[n]) * scale, bf16 out
//   128x128 tile, XOR-SWIZZLED LDS (R9: conflicts 8.26M -> fixed).
//   z==2 (V): position rows (>=2048) never consumed -> early exit.
// ---------------------------------------------------------------------------
__global__ __launch_bounds__(256) void gemm_qkv(
    const short* __restrict__ Abf, const short* __restrict__ Wbf,
    const float* __restrict__ bq, const float* __restrict__ bk,
    const float* __restrict__ bv,
    short* __restrict__ Qc, short* __restrict__ Kc, short* __restrict__ Vc) {
  __shared__ short As[128 * 64];
  __shared__ short Bs[128 * 64];
  int tid = threadIdx.x;
  int wid = tid >> 6, lane = tid & 63;
  int lr = lane & 15, lg = lane >> 4;
  int wr = wid >> 1, wc = wid & 1;
  int z = blockIdx.z;
  int brow = blockIdx.y * 128;
  if (z == 2 && brow >= 2048) return;   // V pos-rows unused
  const short* W = Wbf + z * 1048576;
  const float* bias = (z == 0) ? bq : (z == 1) ? bk : bv;
  short* C = (z == 0) ? Qc : (z == 1) ? Kc : Vc;
  float scale = (z == 2) ? 1.f : QK_SCALE;
  int bcol = blockIdx.x * 128;

  f32x4 acc[4][4];
  for (int i = 0; i < 4; i++)
    for (int j = 0; j < 4; j++) acc[i][j] = (f32x4){0.f, 0.f, 0.f, 0.f};

  for (int k0 = 0; k0 < 1024; k0 += 64) {
    for (int i = 0; i < 4; i++) {
      int n = i * 256 + wid * 64 + lane;
      int row = n >> 3, cswz = n & 7, cb = cswz ^ (row & 7);
      const short* gA = Abf + (size_t)(brow + row) * 1024 + k0 + cb * 8;
      gload_lds16(gA, &As[(i * 256 + wid * 64) * 8]);
      const short* gB = W + (size_t)(bcol + row) * 1024 + k0 + cb * 8;
      gload_lds16(gB, &Bs[(i * 256 + wid * 64) * 8]);
    }
    __syncthreads();
    for (int ks = 0; ks < 2; ks++) {
      s8v af[4], bfv[4];
      for (int mi = 0; mi < 4; mi++) {
        int row = wr * 64 + mi * 16 + lr, cb = ks * 4 + lg;
        af[mi] = *(const s8v*)&As[row * 64 + (cb ^ (row & 7)) * 8];
      }
      for (int ni = 0; ni < 4; ni++) {
        int row = wc * 64 + ni * 16 + lr, cb = ks * 4 + lg;
        bfv[ni] = *(const s8v*)&Bs[row * 64 + (cb ^ (row & 7)) * 8];
      }
      for (int mi = 0; mi < 4; mi++)
        for (int ni = 0; ni < 4; ni++)
          acc[mi][ni] = __builtin_amdgcn_mfma_f32_16x16x32_bf16(
              af[mi], bfv[ni], acc[mi][ni], 0, 0, 0);
    }
    __syncthreads();
  }
  for (int mi = 0; mi < 4; mi++)
    for (int ni = 0; ni < 4; ni++) {
      int col = bcol + wc * 64 + ni * 16 + lr;
      float bb = bias[col];
      for (int r = 0; r < 4; r++) {
        int row = brow + wr * 64 + mi * 16 + lg * 4 + r;
        float v = (acc[mi][ni][r] + bb) * scale;
        C[(size_t)row * 1024 + col] = (short)f2bf(v);
      }
    }
}

// ---------------------------------------------------------------------------
// pos_trans: MERGED pos_gemm (z<64) + transpose_v (z>=64).
//   pos part XOR-SWIZZLED (same fix as gemm_qkv R9).
//   pos part:  which=0: c2p[bh][q][p] = Q[q].posK[p]
//              which=1: p2c[bh][k][p] = K[k].posQ[p] + mbias[b,k]
//   trans part: Vt[b,h,d,l] = Vc[b*1024+l, h*64+d]
// ---------------------------------------------------------------------------
__global__ __launch_bounds__(256) void pos_trans(
    const short* __restrict__ Qc, const short* __restrict__ Kc,
    const short* __restrict__ Vc, const float* __restrict__ mbias,
    short* __restrict__ c2p, short* __restrict__ p2c,
    short* __restrict__ Vt) {
  __shared__ short sh[2 * 128 * 64];
  int tid = threadIdx.x;
  if (blockIdx.z < 64) {
    short* As = sh;
    short* Bs = sh + 128 * 64;
    int wid = tid >> 6, lane = tid & 63;
    int lr = lane & 15, lg = lane >> 4;
    int wr = wid >> 1, wc = wid & 1;
    int zz = blockIdx.z;       // 0..63
    int which = zz >> 5;
    int bh = zz & 31;
    int b = bh >> 4, h = bh & 15;
    const short* Arows = (which == 0) ? Qc : Kc;   // content source
    const short* Brows = (which == 0) ? Kc : Qc;   // pos-projection source
    short* Out = (which == 0) ? c2p : p2c;
    int mrow = blockIdx.y * 128;   // content base (1024/128 = 8)
    int ncol = blockIdx.x * 128;   // bucket base  (512/128 = 4)

    for (int i = 0; i < 4; i++) {
      int n = i * 256 + wid * 64 + lane;
      int row = n >> 3, cswz = n & 7, cb = cswz ^ (row & 7);
      const short* gA = Arows + (size_t)(b * 1024 + mrow + row) * 1024 + h * 64 + cb * 8;
      gload_lds16(gA, &As[(i * 256 + wid * 64) * 8]);
      const short* gB = Brows + (size_t)(2048 + ncol + row) * 1024 + h * 64 + cb * 8;
      gload_lds16(gB, &Bs[(i * 256 + wid * 64) * 8]);
    }
    __syncthreads();

    f32x4 acc[4][4];
    for (int i = 0; i < 4; i++)
      for (int j = 0; j < 4; j++) acc[i][j] = (f32x4){0.f, 0.f, 0.f, 0.f};
    for (int ks = 0; ks < 2; ks++) {
      s8v af[4], bfv[4];
      for (int mi = 0; mi < 4; mi++) {   // A-operand = content rows
        int row = wr * 64 + mi * 16 + lr, cb = ks * 4 + lg;
        af[mi] = *(const s8v*)&As[row * 64 + (cb ^ (row & 7)) * 8];
      }
      for (int ni = 0; ni < 4; ni++) {   // B-operand = bucket rows
        int row = wc * 64 + ni * 16 + lr, cb = ks * 4 + lg;
        bfv[ni] = *(const s8v*)&Bs[row * 64 + (cb ^ (row & 7)) * 8];
      }
      for (int mi = 0; mi < 4; mi++)
        for (int ni = 0; ni < 4; ni++)
          acc[mi][ni] = __builtin_amdgcn_mfma_f32_16x16x32_bf16(
              af[mi], bfv[ni], acc[mi][ni], 0, 0, 0);
    }
    size_t base = (size_t)(b * 16 + h) * 1024;
    for (int mi = 0; mi < 4; mi++)
      for (int ni = 0; ni < 4; ni++)
        for (int r = 0; r < 4; r++) {
          int m = mrow + wr * 64 + mi * 16 + lg * 4 + r;   // content row
          int nn = ncol + wc * 64 + ni * 16 + lr;          // bucket col
          float v = acc[mi][ni][r];
          if (which == 1) v += mbias[b * 1024 + m];
          Out[(base + m) * 512 + nn] = (short)f2bf(v);
        }
  } else {
    short* TL = sh;   // 64*72 elems
    int idx = ((blockIdx.z - 64) * 8 + blockIdx.y) * 4 + blockIdx.x;  // 0..511
    int b = idx >> 8, h = (idx >> 4) & 15, lt = idx & 15;
    for (int i = 0; i < 2; i++) {
      int n = i * 256 + tid;
      int l = n >> 3, c = n & 7;
      s8v v = *(const s8v*)&Vc[(size_t)(b * 1024 + lt * 64 + l) * 1024 + h * 64 + c * 8];
      *(s8v*)&TL[l * 72 + c * 8] = v;
    }
    __syncthreads();
    for (int i = 0; i < 2; i++) {
      int m = i * 256 + tid;
      int d = m >> 3, c = m & 7;
      s8v o;
      for (int jj = 0; jj < 8; jj++) o[jj] = TL[(c * 8 + jj) * 72 + d];
      *(s8v*)&Vt[((size_t)(b * 16 + h) * 64 + d) * 1024 + lt * 64 + c * 8] = o;
    }
  }
}

// ---------------------------------------------------------------------------
// bias_build: block = one 64x64 (q,k) tile of one (b,h). Materializes
//   bias[q,k] = c2p[q][T[q-k]] + p2c[k][T[q-k]]  (mask already in p2c)
//   in MFMA FRAGMENT ORDER so attn reads it with 2 coalesced dwordx4/lane.
// ---------------------------------------------------------------------------
__global__ __launch_bounds__(256) void bias_build(
    const short* __restrict__ c2p, const short* __restrict__ p2c,
    const short* __restrict__ Tt, short* __restrict__ bias) {
  __shared__ short Wc[64 * 66];
  __shared__ short Wp[64 * 66];
  __shared__ short Tl[128];
  int tid = threadIdx.x;
  int wid = tid >> 6, lane = tid & 63;
  int lr = lane & 15, lg = lane >> 4;
  int qt = blockIdx.x, kt = blockIdx.y, bh = blockIdx.z;
  int q0 = qt * 64, k0 = kt * 64;
  int relbase = q0 - k0;
  size_t bh1024 = (size_t)bh * 1024;

  // Tl[i] = T[relbase - 63 + i], i in [0,126]; Tt index = rel + 1023
  if (tid < 127) Tl[tid] = Tt[relbase + 960 + tid];
  __syncthreads();

#pragma unroll
  for (int ii = 0; ii < 16; ii++) {
    int row = wid * 16 + ii;                 // uniform within wave
    int w0 = Tl[row];                        // window base for c2p row
    int col = w0 + lane; col = col > 511 ? 511 : col;
    Wc[row * 66 + lane] = c2p[(bh1024 + q0 + row) * 512 + col];
    int w0p_ = Tl[63 - row];                 // window base for p2c row
    int colp = w0p_ + lane; colp = colp > 511 ? 511 : colp;
    Wp[row * 66 + lane] = p2c[(bh1024 + k0 + row) * 512 + colp];
  }
  __syncthreads();

  int w0c[4], w0p[4];
#pragma unroll
  for (int r = 0; r < 4; r++) w0c[r] = Tl[wid * 16 + lg * 4 + r];
#pragma unroll
  for (int n = 0; n < 4; n++) w0p[n] = Tl[63 - (n * 16 + lr)];

  s8v o0, o1;
#pragma unroll
  for (int n = 0; n < 4; n++)
#pragma unroll
    for (int r = 0; r < 4; r++) {
      int qq = wid * 16 + lg * 4 + r;
      int kk = n * 16 + lr;
      int p = Tl[qq - kk + 63];
      float v = bf2f((unsigned short)Wc[qq * 66 + p - w0c[r]]) +
                bf2f((unsigned short)Wp[kk * 66 + p - w0p[n]]);
      short s = (short)f2bf(v);
      if (n < 2) o0[(n & 1) * 4 + r] = s; else o1[(n & 1) * 4 + r] = s;
    }
  size_t tile = ((size_t)bh * 16 + qt) * 16 + kt;
  size_t base = (tile * 4 + wid) * 1024 + lane * 8;
  *(s8v*)&bias[base] = o0;
  *(s8v*)&bias[base + 512] = o1;
}

// ---------------------------------------------------------------------------
// attn_frag32: Q-SPLIT flash attention, NO device-wide partials.
//   Block = 32 q-rows x FULL K (grid 32x16x2 = 1024 blocks, same occupancy
//   as the old K-split). Waves 0,1 own q-sub {0,16} for k in [0,512);
//   waves 2,3 own the same q-subs for k in [512,1024). Per k-tile only the
//   matching wave-pair computes; all waves co-stage. The two k-halves meet
//   in a block-local LDS combine (reusing Kl/Vl) -> combine kernel and
//   Opart/dpart traffic deleted (R12 showed device-scope fencing is fatal;
//   block-local exchange is free).
// ---------------------------------------------------------------------------
__global__ __launch_bounds__(256) void attn_frag32(
    const short* __restrict__ Qc, const short* __restrict__ Kc,
    const short* __restrict__ Vt, const short* __restrict__ bias,
    float* __restrict__ out) {
  __shared__ short Kl[2][64 * 64];
  __shared__ short Vl[2][64 * 64];
  __shared__ short Pl[4][16 * 64];
  int tid = threadIdx.x;
  int wid = tid >> 6, lane = tid & 63;
  int lr = lane & 15, lg = lane >> 4;
  int qt = blockIdx.x, h = blockIdx.y, b = blockIdx.z;   // qt in [0,32)
  int qsub = wid & 1, khalf = wid >> 1;
  int qbase = qt * 32 + qsub * 16;                        // wave's 16 q rows
  int quarter = (qt & 1) * 2 + qsub;                      // q-quarter in 64-tile
  size_t bh16 = (size_t)(b * 16 + h);

  // Q fragments (held in registers for the whole kernel)
  s8v aq[2];
  for (int s_ = 0; s_ < 2; s_++)
    aq[s_] = *(const s8v*)&Qc[(size_t)(b * 1024 + qbase + lr) * 1024 + h * 64 + s_ * 32 + lg * 8];

  f32x4 oacc[4];
  for (int n = 0; n < 4; n++) oacc[n] = (f32x4){0.f, 0.f, 0.f, 0.f};
  float dsum[4] = {0.f, 0.f, 0.f, 0.f};

  auto stage = [&](int t, int buf) {
#pragma unroll
    for (int i = 0; i < 2; i++) {
      int n = i * 256 + tid;
      int row = n >> 3, cswz = n & 7, cb = cswz ^ (row & 7);
      gload_lds16(&Kc[(size_t)(b * 1024 + t * 64 + row) * 1024 + h * 64 + cb * 8],
                  &Kl[buf][(i * 256 + wid * 64) * 8]);
      gload_lds16(&Vt[(bh16 * 64 + row) * 1024 + t * 64 + cb * 8],
                  &Vl[buf][(i * 256 + wid * 64) * 8]);
    }
  };
  auto fload = [&](int t, s8v& f0, s8v& f1) {
    size_t tile = (bh16 * 16 + (qt >> 1)) * 16 + t;
    size_t base = (tile * 4 + quarter) * 1024 + lane * 8;
    f0 = *(const s8v*)&bias[base];
    f1 = *(const s8v*)&bias[base + 512];
  };

  s8v fb0, fb1, fn0, fn1;
  stage(0, 0);
  if (khalf == 0) fload(0, fb0, fb1);
  __syncthreads();   // drains stage(0)+fload(0)

#pragma unroll
  for (int t = 0; t < 16; ++t) {
    const int cur = t & 1, nxt = cur ^ 1;
    const bool active = ((t >> 3) == khalf);

    // A) issue next tile's async loads FIRST — overlap this tile's compute
    if (t + 1 < 16) {
      stage(t + 1, nxt);
      if (((t + 1) >> 3) == khalf) fload(t + 1, fn0, fn1);
    }

    if (active) {
      // B) S = Q . K^T  (wave: 16 q x 64 k) from Kl[cur]
      f32x4 sacc[4];
#pragma unroll
      for (int n = 0; n < 4; n++) sacc[n] = (f32x4){0.f, 0.f, 0.f, 0.f};
#pragma unroll
      for (int s_ = 0; s_ < 2; s_++)
#pragma unroll
        for (int n = 0; n < 4; n++) {
          int row = n * 16 + lr, cb = s_ * 4 + lg, cbs = cb ^ (row & 7);
          s8v bk_ = *(const s8v*)&Kl[cur][row * 64 + cbs * 8];
          sacc[n] = __builtin_amdgcn_mfma_f32_16x16x32_bf16(aq[s_], bk_, sacc[n], 0, 0, 0);
        }

      // C) add fragment bias (registers), exp, write P (chunk-XOR swizzled)
#pragma unroll
      for (int n = 0; n < 4; n++)
#pragma unroll
        for (int r = 0; r < 4; r++) {
          unsigned short bv_ = (unsigned short)((n < 2 ? fb0 : fb1)[(n & 1) * 4 + r]);
          float p = __expf(sacc[n][r] + bf2f(bv_));
          dsum[r] += p;
          int prow = lg * 4 + r, pc = n * 16 + lr;
          int pcb = (pc >> 3) ^ (prow & 7);
          Pl[wid][prow * 64 + pcb * 8 + (pc & 7)] = (short)f2bf(p);
        }
      asm volatile("s_waitcnt lgkmcnt(0)" ::: "memory");

      // D) O += P . Vt^T  (wave: 16 q x 64 d) from Vl[cur]
#pragma unroll
      for (int s_ = 0; s_ < 2; s_++) {
        int pcb = (s_ * 4 + lg) ^ (lr & 7);
        s8v ap = *(const s8v*)&Pl[wid][lr * 64 + pcb * 8];
#pragma unroll
        for (int n = 0; n < 4; n++) {
          int row = n * 16 + lr, cb = s_ * 4 + lg, cbs = cb ^ (row & 7);
          s8v bv_ = *(const s8v*)&Vl[cur][row * 64 + cbs * 8];
          oacc[n] = __builtin_amdgcn_mfma_f32_16x16x32_bf16(ap, bv_, oacc[n], 0, 0, 0);
        }
      }
    }

    // E) single barrier per tile
    __syncthreads();

    // F) rotate prefetched fragments
    fb0 = fn0; fb1 = fn1;
  }

  // reduce denominators across the 16 lr-lanes sharing the same q rows
  for (int m = 1; m < 16; m <<= 1)
    for (int r = 0; r < 4; r++) dsum[r] += __shfl_xor(dsum[r], m, 64);

  // block-local combine of the two k-halves via LDS (reuse Kl/Vl space)
  float* Ol = (float*)&Kl[0][0];   // 4 waves x 16 rows x 64 cols f32 = 16 KB
  float* Dl = (float*)&Pl[0][0];   // 4 waves x 16 rows f32
  for (int n = 0; n < 4; n++)
    for (int r = 0; r < 4; r++)
      Ol[wid * 1024 + (lg * 4 + r) * 64 + n * 16 + lr] = oacc[n][r];
  if (lr == 0)
    for (int r = 0; r < 4; r++) Dl[wid * 16 + lg * 4 + r] = dsum[r];
  __syncthreads();
  if (khalf == 0) {
    int pw = wid + 2;   // partner wave (same q rows, other k-half)
    float dtot[4];
    for (int r = 0; r < 4; r++) dtot[r] = dsum[r] + Dl[pw * 16 + lg * 4 + r];
    for (int n = 0; n < 4; n++)
      for (int r = 0; r < 4; r++) {
        float o = oacc[n][r] + Ol[pw * 1024 + (lg * 4 + r) * 64 + n * 16 + lr];
        int q = qbase + lg * 4 + r;
        out[(size_t)(b * 1024 + q) * 1024 + h * 64 + n * 16 + lr] = o / dtot[r];
      }
  }
}

// ---------------------------------------------------------------------------
// attn_gather: fallback (used only if workspace too small for bias_frag)
// ---------------------------------------------------------------------------
template <int NSPLIT>
__global__ __launch_bounds__(256) void attn_gather(
    const short* __restrict__ Qc, const short* __restrict__ Kc,
    const short* __restrict__ Vt, const short* __restrict__ c2p,
    const short* __restrict__ p2c, const short* __restrict__ Tt,
    float* __restrict__ Opart, float* __restrict__ dpart,
    float* __restrict__ out) {
  const int KSEG = 1024 / NSPLIT;
  const int NT = KSEG / 64;
  const int TLN = 64 + KSEG - 1;
  __shared__ short Kl[2][64 * 64];
  __shared__ short Vl[2][64 * 64];
  __shared__ short Pl[4][16 * 72];
  __shared__ short Tl[TLN + 1];
  int tid = threadIdx.x;
  int wid = tid >> 6, lane = tid & 63;
  int lr = lane & 15, lg = lane >> 4;
  int qt = blockIdx.x, h = blockIdx.y, z = blockIdx.z;
  int b = (NSPLIT == 1) ? z : (z / NSPLIT);
  int ks = (NSPLIT == 1) ? 0 : (z % NSPLIT);
  int k0seg = ks * KSEG;
  int q0 = qt * 64, qbase = q0 + wid * 16;
  size_t bh1024 = (size_t)(b * 16 + h) * 1024;

  for (int i = tid; i < TLN; i += 256) Tl[i] = Tt[(q0 - k0seg - (KSEG - 1) + 1023) + i];

  s8v aq[2];
  for (int s_ = 0; s_ < 2; s_++)
    aq[s_] = *(const s8v*)&Qc[(size_t)(b * 1024 + qbase + lr) * 1024 + h * 64 + s_ * 32 + lg * 8];

  f32x4 oacc[4];
  for (int n = 0; n < 4; n++) oacc[n] = (f32x4){0.f, 0.f, 0.f, 0.f};
  float dsum[4] = {0.f, 0.f, 0.f, 0.f};
  __syncthreads();

  auto stage = [&](int t, int buf) {
#pragma unroll
    for (int i = 0; i < 2; i++) {
      int n = i * 256 + tid;
      int row = n >> 3, cswz = n & 7, cb = cswz ^ (row & 7);
      gload_lds16(&Kc[(size_t)(b * 1024 + k0seg + t * 64 + row) * 1024 + h * 64 + cb * 8],
                  &Kl[buf][(i * 256 + wid * 64) * 8]);
      gload_lds16(&Vt[((size_t)(b * 16 + h) * 64 + row) * 1024 + k0seg + t * 64 + cb * 8],
                  &Vl[buf][(i * 256 + wid * 64) * 8]);
    }
  };
  auto gather = [&](int t, unsigned short* cg, unsigned short* pg) {
#pragma unroll
    for (int n = 0; n < 4; n++) {
      int k = k0seg + t * 64 + n * 16 + lr;
      size_t prow = (bh1024 + k) * 512;
      int jb = wid * 16 - t * 64 - lr + (KSEG - 1) - n * 16 + lg * 4;
#pragma unroll
      for (int r = 0; r < 4; r++) {
        int q = qbase + lg * 4 + r;
        int idx = Tl[jb + r];
        cg[n * 4 + r] = (unsigned short)c2p[(bh1024 + q) * 512 + idx];
        pg[n * 4 + r] = (unsigned short)p2c[prow + idx];
      }
    }
  };

  unsigned short c2g[16], p2g[16], c2n[16], p2n[16];
  stage(0, 0);
  gather(0, c2g, p2g);
  __syncthreads();

#pragma unroll
  for (int t = 0; t < NT; ++t) {
    const int cur = t & 1, nxt = cur ^ 1;
    if (t + 1 < NT) { stage(t + 1, nxt); gather(t + 1, c2n, p2n); }

    f32x4 sacc[4];
#pragma unroll
    for (int n = 0; n < 4; n++) sacc[n] = (f32x4){0.f, 0.f, 0.f, 0.f};
#pragma unroll
    for (int s_ = 0; s_ < 2; s_++)
#pragma unroll
      for (int n = 0; n < 4; n++) {
        int row = n * 16 + lr, cb = s_ * 4 + lg, cbs = cb ^ (row & 7);
        s8v bk_ = *(const s8v*)&Kl[cur][row * 64 + cbs * 8];
        sacc[n] = __builtin_amdgcn_mfma_f32_16x16x32_bf16(aq[s_], bk_, sacc[n], 0, 0, 0);
      }
#pragma unroll
    for (int n = 0; n < 4; n++)
#pragma unroll
      for (int r = 0; r < 4; r++) {
        float bias = bf2f(c2g[n * 4 + r]) + bf2f(p2g[n * 4 + r]);
        float p = __expf(sacc[n][r] + bias);
        dsum[r] += p;
        Pl[wid][(lg * 4 + r) * 72 + n * 16 + lr] = (short)f2bf(p);
      }
    asm volatile("s_waitcnt lgkmcnt(0)" ::: "memory");
#pragma unroll
    for (int s_ = 0; s_ < 2; s_++) {
      s8v ap = *(const s8v*)&Pl[wid][lr * 72 + s_ * 32 + lg * 8];
#pragma unroll
      for (int n = 0; n < 4; n++) {
        int row = n * 16 + lr, cb = s_ * 4 + lg, cbs = cb ^ (row & 7);
        s8v bv_ = *(const s8v*)&Vl[cur][row * 64 + cbs * 8];
        oacc[n] = __builtin_amdgcn_mfma_f32_16x16x32_bf16(ap, bv_, oacc[n], 0, 0, 0);
      }
    }
    __syncthreads();
    if (t + 1 < NT) {
#pragma unroll
      for (int i = 0; i < 16; i++) { c2g[i] = c2n[i]; p2g[i] = p2n[i]; }
    }
  }

  for (int m = 1; m < 16; m <<= 1)
    for (int r = 0; r < 4; r++) dsum[r] += __shfl_xor(dsum[r], m, 64);

  if (NSPLIT == 1) {
    for (int n = 0; n < 4; n++)
      for (int r = 0; r < 4; r++) {
        int q = qbase + lg * 4 + r;
        int d = n * 16 + lr;
        out[(size_t)(b * 1024 + q) * 1024 + h * 64 + d] = oacc[n][r] / dsum[r];
      }
  } else {
    size_t po = ((size_t)(z * 16 + h)) * 65536;
    for (int n = 0; n < 4; n++)
      for (int r = 0; r < 4; r++) {
        int q = qbase + lg * 4 + r;
        Opart[po + (size_t)q * 64 + n * 16 + lr] = oacc[n][r];
      }
    if (lr == 0)
      for (int r = 0; r < 4; r++)
        dpart[(z * 16 + h) * 1024 + qbase + lg * 4 + r] = dsum[r];
  }
}

// ---------------------------------------------------------------------------
// combine: out = sum_ks Opart / sum_ks dpart  (fallback path only)
// ---------------------------------------------------------------------------
template <int NSPLIT>
__global__ __launch_bounds__(256) void combine_kernel(
    const float* __restrict__ Opart, const float* __restrict__ dpart,
    float* __restrict__ out) {
  int idx = blockIdx.x * 256 + threadIdx.x;
  int pos = idx * 4;                 // flat out index, 4 floats per thread
  int b = pos >> 20;
  int q = (pos >> 10) & 1023;
  int hd = pos & 1023;
  int h = hd >> 6, d = hd & 63;
  f4v s = (f4v){0.f, 0.f, 0.f, 0.f};
  float dn = 0.f;
  for (int ks = 0; ks < NSPLIT; ks++) {
    int zh = (b * NSPLIT + ks) * 16 + h;
    s += *(const f4v*)&Opart[(size_t)zh * 65536 + q * 64 + d];
    dn += dpart[zh * 1024 + q];
  }
  f4v r = s / dn;
  *(f4v*)&out[pos] = r;
}

// ---------------------------------------------------------------------------
extern "C" void kernel_launch(void* const* d_in, const int* in_sizes, int n_in,
                              void* d_out, int out_size, void* d_ws, size_t ws_size,
                              hipStream_t stream) {
  (void)in_sizes; (void)n_in; (void)out_size;
  const float* hidden = (const float*)d_in[0];
  const int* mask = (const int*)d_in[1];
  const float* rel = (const float*)d_in[2];
  const float* Wq = (const float*)d_in[3];
  const float* bq = (const float*)d_in[4];
  const float* Wk = (const float*)d_in[5];
  const float* bk = (const float*)d_in[6];
  const float* Wv = (const float*)d_in[7];
  const float* bv = (const float*)d_in[8];
  float* out = (float*)d_out;

  char* w = (char*)d_ws;
  short* Abf = (short*)w; w += 2560 * 1024 * 2;          // 5.25 MB
  short* Wbf = (short*)w; w += 3 * 1024 * 1024 * 2;      // 6.29 MB
  short* Qc  = (short*)w; w += 2560 * 1024 * 2;
  short* Kc  = (short*)w; w += 2560 * 1024 * 2;
  short* Vc  = (short*)w; w += 2560 * 1024 * 2;
  short* Vt  = (short*)w; w += 2 * 16 * 64 * 1024 * 2;   // 4.19 MB
  short* c2p = (short*)w; w += (size_t)2 * 16 * 1024 * 512 * 2;  // 33.5 MB
  short* p2c = (short*)w; w += (size_t)2 * 16 * 1024 * 512 * 2;  // 33.5 MB
  short* Tt  = (short*)w; w += 4096;
  float* mbias = (float*)w; w += 8192;
  // frag path: bias matrix appended; attn_frag32 writes out directly.
  short* bias_frag = (short*)w;
  size_t need_frag = (size_t)(w - (char*)d_ws) + (size_t)8192 * 4096 * 2;  // +67.1 MB
  // gather path: Opart/dpart appended (c2p/p2c stay live through attn).
  float* Opart_old = (float*)w;
  size_t need_old = (size_t)(w - (char*)d_ws) + (size_t)8 * 16 * 1024 * 64 * 4 + 8 * 16 * 1024 * 4;

  prep_kernel<<<5648, 256, 0, stream>>>(hidden, rel, Wq, Wk, Wv, mask, Abf, Wbf, mbias, Tt);
  gemm_qkv<<<dim3(8, 20, 3), 256, 0, stream>>>(Abf, Wbf, bq, bk, bv, Qc, Kc, Vc);
  pos_trans<<<dim3(4, 8, 80), 256, 0, stream>>>(Qc, Kc, Vc, mbias, c2p, p2c, Vt);

  if (ws_size >= need_frag) {
    bias_build<<<dim3(16, 16, 32), 256, 0, stream>>>(c2p, p2c, Tt, bias_frag);
    attn_frag32<<<dim3(32, 16, 2), 256, 0, stream>>>(Qc, Kc, Vt, bias_frag, out);
  } else if (ws_size >= need_old) {
    float* Opart = Opart_old;
    float* dpart = (float*)((char*)Opart_old + (size_t)8 * 16 * 1024 * 64 * 4);
    attn_gather<4><<<dim3(16, 16, 8), 256, 0, stream>>>(Qc, Kc, Vt, c2p, p2c, Tt,
                                                        Opart, dpart, out);
    combine_kernel<4><<<2048, 256, 0, stream>>>(Opart, dpart, out);
  } else {
    attn_gather<1><<<dim3(16, 16, 2), 256, 0, stream>>>(Qc, Kc, Vt, c2p, p2c, Tt,
                                                        (float*)Opart_old, (float*)Opart_old, out);
  }
}